// Round 1
// 502.802 us; speedup vs baseline: 1.0377x; 1.0377x over previous
//
#include <hip/hip_runtime.h>
#include <hip/hip_bf16.h>

#define DEVINL __device__ __forceinline__

constexpr int N  = 50000;
constexpr int E  = 600000;
constexpr int TE = E + N;      // edges + self loops
constexpr int D  = 128;
constexpr int SCAN_B = (N + 255) / 256;   // 196 blocks for hierarchical scan
constexpr int GEMM_ROWS = 64;             // 16 rows per wave, 4 waves
constexpr int GEMM_B = (N + GEMM_ROWS - 1) / GEMM_ROWS;  // 782
constexpr int HST_STRIDE = 136;           // ushorts; quad-staggered banks, 16B-aligned

typedef short bf16x8 __attribute__((ext_vector_type(8)));
typedef float f32x4  __attribute__((ext_vector_type(4)));

DEVINL float lrelu(float x, float s) { return x >= 0.f ? x : s * x; }

DEVINL unsigned short f2bf(float f) {   // RNE fp32 -> bf16
    unsigned u = __float_as_uint(f);
    u += 0x7FFFu + ((u >> 16) & 1u);
    return (unsigned short)(u >> 16);
}
DEVINL float bfl(unsigned u) { return __uint_as_float(u << 16); }          // low bf16
DEVINL float bfh(unsigned u) { return __uint_as_float(u & 0xFFFF0000u); }  // high bf16

// ---------- W -> bf16 copy for all 3 layers (layout unchanged: Wb[o][k]) ----------
__global__ __launch_bounds__(256) void k_wb3(const float* __restrict__ W0,
                                             const float* __restrict__ W1,
                                             const float* __restrict__ W2,
                                             unsigned short* __restrict__ Wb) {
    int b = blockIdx.x;          // 192 blocks: 64 per layer
    int l = b >> 6;
    const float* W = (l == 0) ? W0 : (l == 1) ? W1 : W2;
    int t = (b & 63) * 256 + threadIdx.x;   // 0..16383
    Wb[l * 16384 + t] = f2bf(W[t]);
}

// ---------- MFMA GEMM: H[v,o] = sum_k BN(Xin)[v,k] * W[o,k]  (bf16 in, fp32 acc) ----------
// apply_bn=0: input = fp32 X. apply_bn=1: input = bf16 O16; BN scale/shift computed
// per-block from colsum/colsq (replaces the separate k_bnfinal launch — R15).
// R16: aj is stored interleaved at ajx[2*row] (ajx[2*row+1] = invden, filled by k_den)
// so k_aggregate can gather (aj, invden) as one float2.
__global__ __launch_bounds__(256) void k_gemm(const float* __restrict__ X,
                                              const unsigned short* __restrict__ O16,
                                              const unsigned short* __restrict__ Wb,
                                              unsigned short* __restrict__ Hb16,
                                              const float* __restrict__ att,
                                              float* __restrict__ ai,
                                              float* __restrict__ ajx,
                                              const float* __restrict__ csum,
                                              const float* __restrict__ csq,
                                              const float* __restrict__ g,
                                              const float* __restrict__ be,
                                              int apply_bn) {
    __shared__ unsigned short hst[4][16][HST_STRIDE];   // ~17 KB
    __shared__ float ssl[256];                          // scale[128], shift[128]
    int wave = threadIdx.x >> 6, lane = threadIdx.x & 63;
    int m = lane & 15, quad = lane >> 4;
    int r0 = blockIdx.x * GEMM_ROWS + wave * 16;

    if (apply_bn) {
        if (threadIdx.x < 128) {
            int c = threadIdx.x;
            float mean = csum[c] / (float)N;
            float var  = csq[c] / (float)N - mean * mean;
            float scale = g[c] * rsqrtf(var + 1e-5f);
            ssl[c] = scale;
            ssl[128 + c] = be[c] - mean * scale;
        }
        __syncthreads();
    }

    // ---- A fragments for 4 K-steps ----
    bf16x8 afrag[4];
    int rowA = r0 + m;
    bool rowok = rowA < N;
    #pragma unroll
    for (int k4 = 0; k4 < 4; k4++) {
        int c0 = k4 * 32 + quad * 8;   // feature column of first element
        float v[8];
        if (rowok) {
            if (apply_bn) {
                uint4 hu = *(const uint4*)(O16 + (size_t)rowA * D + c0);
                v[0] = bfl(hu.x); v[1] = bfh(hu.x);
                v[2] = bfl(hu.y); v[3] = bfh(hu.y);
                v[4] = bfl(hu.z); v[5] = bfh(hu.z);
                v[6] = bfl(hu.w); v[7] = bfh(hu.w);
                #pragma unroll
                for (int j = 0; j < 8; j++)
                    v[j] = lrelu(v[j] * ssl[c0 + j] + ssl[128 + c0 + j], 0.1f);
            } else {
                float4 x0 = *(const float4*)(X + (size_t)rowA * D + c0);
                float4 x1 = *(const float4*)(X + (size_t)rowA * D + c0 + 4);
                v[0] = x0.x; v[1] = x0.y; v[2] = x0.z; v[3] = x0.w;
                v[4] = x1.x; v[5] = x1.y; v[6] = x1.z; v[7] = x1.w;
            }
        } else {
            #pragma unroll
            for (int j = 0; j < 8; j++) v[j] = 0.f;
        }
        #pragma unroll
        for (int j = 0; j < 8; j++) afrag[k4][j] = (short)f2bf(v[j]);
    }

    // ---- 8 col-tiles of 16, K=128 via 4 MFMA each ----
    float pii[4] = {0.f, 0.f, 0.f, 0.f};
    float pjj[4] = {0.f, 0.f, 0.f, 0.f};
    #pragma unroll
    for (int nt = 0; nt < 8; nt++) {
        int n0 = nt * 16;
        f32x4 acc = {0.f, 0.f, 0.f, 0.f};
        const unsigned short* wrow = Wb + (size_t)(n0 + m) * D + quad * 8;
        #pragma unroll
        for (int k4 = 0; k4 < 4; k4++) {
            bf16x8 b = *(const bf16x8*)(wrow + k4 * 32);
            acc = __builtin_amdgcn_mfma_f32_16x16x32_bf16(afrag[k4], b, acc, 0, 0, 0);
        }
        float ad = att[n0 + m];
        float as = att[128 + n0 + m];
        #pragma unroll
        for (int i = 0; i < 4; i++) {
            hst[wave][quad * 4 + i][n0 + m] = f2bf(acc[i]);
            pii[i] += acc[i] * ad;
            pjj[i] += acc[i] * as;
        }
    }

    // ---- coalesced H flush: lane reads 16B of a staged row, dwordx4 store ----
    #pragma unroll
    for (int t = 0; t < 4; t++) {
        int r = t * 4 + quad;              // 0..15 within wave tile
        int row = r0 + r;
        int cb = m * 8;                    // ushort col base (16 B)
        uint4 vv = *(const uint4*)&hst[wave][r][cb];
        if (row < N)
            *(uint4*)(Hb16 + (size_t)row * D + cb) = vv;
    }

    // ---- reduce attention dots across the 16 lanes of each quad ----
    #pragma unroll
    for (int mask = 8; mask >= 1; mask >>= 1) {
        #pragma unroll
        for (int i = 0; i < 4; i++) {
            pii[i] += __shfl_xor(pii[i], mask);
            pjj[i] += __shfl_xor(pjj[i], mask);
        }
    }
    if (m == 0) {
        #pragma unroll
        for (int i = 0; i < 4; i++) {
            int row = r0 + quad * 4 + i;
            if (row < N) { ai[row] = pii[i]; ajx[2 * (size_t)row] = pjj[i]; }
        }
    }
}

DEVINL void edge_sd(int e, const int* ei, int& s, int& d) {
    if (e < E) { s = ei[e]; d = ei[E + e]; }
    else       { s = d = e - E; }
}

// ---------- dual CSR build (once; graph shared across layers) ----------
// R16: also build the src-keyed CSR so the softmax denominator (segmented by SRC
// in the reference) becomes an atomic-free per-node reduction instead of 650k
// device-scope float far-atomics per layer (rocprof: 21.8MB write-through in
// k_edge_soft = 32B/atomic to the far coherent point).
__global__ __launch_bounds__(256) void k_deg2(const int* __restrict__ ei,
                                              int* __restrict__ degd,
                                              int* __restrict__ degs) {
    int e = blockIdx.x * 256 + threadIdx.x;
    if (e >= TE) return;
    int s, d; edge_sd(e, ei, s, d);
    atomicAdd(degd + d, 1);
    atomicAdd(degs + s, 1);
}

__global__ __launch_bounds__(256) void k_scan1(const int* __restrict__ deg, int* __restrict__ bsum) {
    __shared__ int red[256];
    int t = threadIdx.x;
    int v = blockIdx.x * 256 + t;
    red[t] = (v < N) ? deg[v] : 0;
    __syncthreads();
    #pragma unroll
    for (int off = 128; off; off >>= 1) {
        if (t < off) red[t] += red[t + off];
        __syncthreads();
    }
    if (t == 0) bsum[blockIdx.x] = red[0];
}

__global__ __launch_bounds__(256) void k_scan2(const int* __restrict__ bsum,
                                               int* __restrict__ boff, int* __restrict__ row_ptr) {
    __shared__ int sc[256];
    int t = threadIdx.x;
    int v = (t < SCAN_B) ? bsum[t] : 0;
    sc[t] = v;
    __syncthreads();
    #pragma unroll
    for (int off = 1; off < 256; off <<= 1) {
        int add = (t >= off) ? sc[t - off] : 0;
        __syncthreads();
        sc[t] += add;
        __syncthreads();
    }
    if (t < SCAN_B) boff[t] = sc[t] - v;       // exclusive
    if (t == SCAN_B - 1) row_ptr[N] = sc[t];   // total = TE
}

__global__ __launch_bounds__(256) void k_scan3(const int* __restrict__ deg,
                                               const int* __restrict__ boff,
                                               int* __restrict__ row_ptr) {
    __shared__ int sc[256];
    int t = threadIdx.x;
    int v = blockIdx.x * 256 + t;
    int d = (v < N) ? deg[v] : 0;
    sc[t] = d;
    __syncthreads();
    #pragma unroll
    for (int off = 1; off < 256; off <<= 1) {
        int add = (t >= off) ? sc[t - off] : 0;
        __syncthreads();
        sc[t] += add;
        __syncthreads();
    }
    if (v < N) row_ptr[v] = boff[blockIdx.x] + sc[t] - d;
}

// ---------- fill both CSRs in one edge pass ----------
__global__ __launch_bounds__(256) void k_fill2(const int* __restrict__ ei,
                                               const int* __restrict__ rowp,
                                               const int* __restrict__ srcp,
                                               int* __restrict__ filld,
                                               int* __restrict__ fills,
                                               int* __restrict__ srcc,
                                               int* __restrict__ dstc) {
    int e = blockIdx.x * 256 + threadIdx.x;
    if (e >= TE) return;
    int s, d; edge_sd(e, ei, s, d);
    int pd = atomicAdd(filld + d, 1);
    srcc[rowp[d] + pd] = s;
    int ps = atomicAdd(fills + s, 1);
    dstc[srcp[s] + ps] = d;
}

// ---------- softmax denominator: 16-lane group per SRC node, no atomics ----------
// den[s] = sum over out-edges (s->d) of exp(lrelu(ai[d] + aj[s])); store 1/den
// interleaved next to aj so the aggregate gather is a single float2.
// Block 0 also zeroes colsum/colsq (256 floats) for this layer's k_stats —
// safe: runs after k_gemm consumed the previous layer's stats (stream order).
__global__ __launch_bounds__(256) void k_den(const int* __restrict__ srcp,
                                             const int* __restrict__ dstc,
                                             const float* __restrict__ ai,
                                             float* __restrict__ ajx,
                                             float* __restrict__ csumz) {
    if (blockIdx.x == 0) csumz[threadIdx.x] = 0.f;
    int g = threadIdx.x >> 4, l16 = threadIdx.x & 15;
    int v = blockIdx.x * 16 + g;
    if (v >= N) return;
    int beg = srcp[v], end = srcp[v + 1];
    float ajv = ajx[2 * (size_t)v];
    float acc = 0.f;
    for (int idx = beg + l16; idx < end; idx += 16) {
        int d = dstc[idx];
        acc += expf(lrelu(ai[d] + ajv, 0.2f));
    }
    #pragma unroll
    for (int mask = 8; mask >= 1; mask >>= 1) acc += __shfl_xor(acc, mask);
    if (l16 == 0) ajx[2 * (size_t)v + 1] = 1.0f / (acc + 1e-16f);
}

// ---------- aggregation: wave per dst node, pair-gather, bf16 O output ----------
// (R9 NOTE: no per-slot clamping in the hot loop — predication before gathers kills MLP.)
// R16: weights computed on the fly: w = exp(lrelu(ai[v]+aj[s])) * invden[s].
// (aj,invden) is one float2 gather; alpha array + k_edge_soft eliminated.
__global__ __launch_bounds__(256) void k_aggregate(const int* __restrict__ rowp,
                                                   const int* __restrict__ srcc,
                                                   const float* __restrict__ ai,
                                                   const float2* __restrict__ ajinv,
                                                   const uint2* __restrict__ Hu2, // 4 bf16 per uint2
                                                   const float* __restrict__ bvec,
                                                   unsigned short* __restrict__ O16) {
    int wid = threadIdx.x >> 6, lane = threadIdx.x & 63;
    int h = lane >> 5, l32 = lane & 31;
    int v = blockIdx.x * 4 + wid;
    if (v >= N) return;
    int beg = rowp[v], end = rowp[v + 1];   // non-empty (self loop)
    float aiv = ai[v];
    float a0 = 0.f, a1 = 0.f, a2 = 0.f, a3 = 0.f;
    int idx = beg;
    for (; idx + 8 <= end; idx += 8) {            // 4 pairs = 8 edges
        int    s[4];
        float2 aw[4];
        uint2  u[4];
        #pragma unroll
        for (int t = 0; t < 4; t++) s[t] = srcc[idx + 2 * t + h];
        #pragma unroll
        for (int t = 0; t < 4; t++) aw[t] = ajinv[s[t]];
        #pragma unroll
        for (int t = 0; t < 4; t++) u[t] = Hu2[(size_t)s[t] * 32 + l32];
        #pragma unroll
        for (int t = 0; t < 4; t++) {
            float w = expf(lrelu(aiv + aw[t].x, 0.2f)) * aw[t].y;
            a0 += w * bfl(u[t].x);
            a1 += w * bfh(u[t].x);
            a2 += w * bfl(u[t].y);
            a3 += w * bfh(u[t].y);
        }
    }
    for (; idx + 2 <= end; idx += 2) {            // pair tail
        int s = srcc[idx + h];
        float2 aw = ajinv[s];
        float w = expf(lrelu(aiv + aw.x, 0.2f)) * aw.y;
        uint2 u = Hu2[(size_t)s * 32 + l32];
        a0 += w * bfl(u.x);
        a1 += w * bfh(u.x);
        a2 += w * bfl(u.y);
        a3 += w * bfh(u.y);
    }
    if (idx < end) {                              // single tail: half 1 weight 0
        int s = srcc[idx];
        float2 aw = ajinv[s];
        float w = (h == 0) ? expf(lrelu(aiv + aw.x, 0.2f)) * aw.y : 0.f;
        uint2 u = Hu2[(size_t)s * 32 + l32];
        a0 += w * bfl(u.x);
        a1 += w * bfh(u.x);
        a2 += w * bfl(u.y);
        a3 += w * bfh(u.y);
    }
    a0 += __shfl_xor(a0, 32);
    a1 += __shfl_xor(a1, 32);
    a2 += __shfl_xor(a2, 32);
    a3 += __shfl_xor(a3, 32);
    if (h == 0) {
        float4 b = ((const float4*)bvec)[l32];
        float o0 = fmaxf(a0 + b.x, 0.f);
        float o1 = fmaxf(a1 + b.y, 0.f);
        float o2 = fmaxf(a2 + b.z, 0.f);
        float o3 = fmaxf(a3 + b.w, 0.f);
        uint2 st;
        st.x = (unsigned)f2bf(o0) | ((unsigned)f2bf(o1) << 16);
        st.y = (unsigned)f2bf(o2) | ((unsigned)f2bf(o3) << 16);
        *(uint2*)(O16 + (size_t)v * D + l32 * 4) = st;
    }
}

// ---------- BN column stats on bf16 O: uint2 per thread (4 cols), LDS reduce ----------
// NOTE (R11): last-block finalize via __threadfence() cost ~35 us/layer on gfx950
// (device-scope fence = per-XCD L2 writeback per block). Finalize lives in consumers.
__global__ __launch_bounds__(256) void k_stats(const unsigned short* __restrict__ O16,
                                               float* __restrict__ colsum, float* __restrict__ colsq) {
    int c4 = (threadIdx.x & 31) * 4;   // column base (4 cols per thread)
    int rg = threadIdx.x >> 5;         // row group 0..7
    float s0=0.f,s1=0.f,s2=0.f,s3=0.f,q0=0.f,q1=0.f,q2=0.f,q3=0.f;
    for (int v = blockIdx.x * 8 + rg; v < N; v += gridDim.x * 8) {
        uint2 u = *(const uint2*)(O16 + (size_t)v * D + c4);
        float v0 = bfl(u.x), v1 = bfh(u.x), v2 = bfl(u.y), v3 = bfh(u.y);
        s0 += v0; q0 += v0 * v0;
        s1 += v1; q1 += v1 * v1;
        s2 += v2; q2 += v2 * v2;
        s3 += v3; q3 += v3 * v3;
    }
    __shared__ float ls[8][128], lq[8][128];   // 8 KB
    ls[rg][c4+0]=s0; ls[rg][c4+1]=s1; ls[rg][c4+2]=s2; ls[rg][c4+3]=s3;
    lq[rg][c4+0]=q0; lq[rg][c4+1]=q1; lq[rg][c4+2]=q2; lq[rg][c4+3]=q3;
    __syncthreads();
    if (threadIdx.x < 128) {
        int c = threadIdx.x;
        float s = 0.f, q = 0.f;
        #pragma unroll
        for (int r = 0; r < 8; r++) { s += ls[r][c]; q += lq[r][c]; }
        atomicAdd(colsum + c, s);
        atomicAdd(colsq + c, q);
    }
}

// ---------- decoder ----------
__global__ __launch_bounds__(256) void k_T(const float* __restrict__ P1, const float* __restrict__ P2,
                                           float* __restrict__ T) {
    int t = blockIdx.x * 256 + threadIdx.x;
    if (t >= 128 * 64) return;
    int i = t >> 6, d = t & 63;
    float s = 0.f;
    #pragma unroll 8
    for (int k = 0; k < 64; k++) s += P1[i * 64 + k] * P2[k * 64 + d];
    T[t] = s;
}

__global__ __launch_bounds__(256) void k_M(const float* __restrict__ T, const float* __restrict__ P1,
                                           float* __restrict__ M) {
    int t = blockIdx.x * 256 + threadIdx.x;
    if (t >= 128 * 128) return;
    int i = t >> 7, j = t & 127;
    float s = 0.f;
    #pragma unroll 8
    for (int d = 0; d < 64; d++) s += T[i * 64 + d] * P1[j * 64 + d];
    M[t] = s;
}

__global__ __launch_bounds__(128) void k_pred(const unsigned short* __restrict__ O16,
                                              const float* __restrict__ csum,
                                              const float* __restrict__ csq,
                                              const float* __restrict__ g,
                                              const float* __restrict__ be,
                                              const int* __restrict__ drug,
                                              const float* __restrict__ M,
                                              float* __restrict__ out) {
    int b = blockIdx.x, i = threadIdx.x;
    __shared__ float av[128], bv[128];
    int ia = drug[b * 2] - 1, ib = drug[b * 2 + 1] - 1;
    float mean = csum[i] / (float)N;
    float var  = csq[i] / (float)N - mean * mean;
    float scale = g[i] * rsqrtf(var + 1e-5f);
    float shift = be[i] - mean * scale;
    float ha = __uint_as_float(((unsigned)O16[(size_t)ia * D + i]) << 16);
    float hb = __uint_as_float(((unsigned)O16[(size_t)ib * D + i]) << 16);
    av[i] = lrelu(ha * scale + shift, 0.1f);
    bv[i] = lrelu(hb * scale + shift, 0.1f);
    __syncthreads();
    const float4* M4  = (const float4*)(M + (size_t)i * 128);
    const float4* bv4 = (const float4*)bv;
    float u = 0.f;
    #pragma unroll 8
    for (int j = 0; j < 32; j++) {
        float4 mv = M4[j];
        float4 bb = bv4[j];
        u += mv.x * bb.x + mv.y * bb.y + mv.z * bb.z + mv.w * bb.w;
    }
    float val = av[i] * u;
    #pragma unroll
    for (int off = 32; off; off >>= 1) val += __shfl_down(val, off);
    __shared__ float red[2];
    if ((i & 63) == 0) red[i >> 6] = val;
    __syncthreads();
    if (i == 0) out[b] = red[0] + red[1];
}

extern "C" void kernel_launch(void* const* d_in, const int* in_sizes, int n_in,
                              void* d_out, int out_size, void* d_ws, size_t ws_size,
                              hipStream_t stream) {
    const float* x    = (const float*)d_in[0];
    const int*   ei   = (const int*)  d_in[1];
    const int*   drug = (const int*)  d_in[2];
    const float* W[3]   = {(const float*)d_in[3], (const float*)d_in[8],  (const float*)d_in[13]};
    const float* att[3] = {(const float*)d_in[4], (const float*)d_in[9],  (const float*)d_in[14]};
    const float* bb[3]  = {(const float*)d_in[5], (const float*)d_in[10], (const float*)d_in[15]};
    const float* gg[3]  = {(const float*)d_in[6], (const float*)d_in[11], (const float*)d_in[16]};
    const float* be[3]  = {(const float*)d_in[7], (const float*)d_in[12], (const float*)d_in[17]};
    const float* P1 = (const float*)d_in[18];
    const float* P2 = (const float*)d_in[19];

    float* ws = (float*)d_ws;
    size_t o_H      = 0;                     // bf16 H: N*128 ushorts = N*64 float slots
    size_t o_O      = o_H + (size_t)N * 64;  // bf16 O: N*128 ushorts = N*64 float slots
    size_t o_ai     = o_O + (size_t)N * 64;
    size_t o_ajinv  = o_ai + N;              // float2 per node: (aj, invden)
    size_t o_colsum = o_ajinv + 2 * (size_t)N;  // 128
    size_t o_colsq  = o_colsum + 128;           // 128
    size_t o_deg    = o_colsq + 128;   // ints: degd[N] degs[N] filld[N] fills[N]
    size_t o_rowptr = o_deg + 4 * (size_t)N;    // int, N+1 (pad 8)
    size_t o_srcp   = o_rowptr + N + 8;         // int, N+1 (pad 8)
    size_t o_src    = o_srcp + N + 8;  // int, TE   (src per dst-CSR slot)
    size_t o_dstc   = o_src + TE;      // int, TE   (dst per src-CSR slot)
    size_t o_bsum   = o_dstc + TE;     // int, SCAN_B (pad to 256)
    size_t o_boff   = o_bsum + 256;    // int, SCAN_B (pad to 256)
    size_t o_T      = o_boff + 256;    // 128*64
    size_t o_Mm     = o_T + 128 * 64;  // 128*128
    size_t o_Wb     = o_Mm + 128 * 128;// 3*16384 ushorts = 24576 floats

    unsigned short* Hb16 = (unsigned short*)(ws + o_H);
    uint2*          Hu2  = (uint2*)(ws + o_H);
    unsigned short* O16  = (unsigned short*)(ws + o_O);
    float*    ai    = ws + o_ai;
    float*    ajx   = ws + o_ajinv;
    float2*   ajinv = (float2*)(ws + o_ajinv);
    float*    csum  = ws + o_colsum;
    float*    csq   = ws + o_colsq;
    int*      degd  = (int*)(ws + o_deg);
    int*      degs  = degd + N;
    int*      filld = degs + N;
    int*      fills = filld + N;
    int*      rowp  = (int*)(ws + o_rowptr);
    int*      srcp  = (int*)(ws + o_srcp);
    int*      srcc  = (int*)(ws + o_src);
    int*      dstc  = (int*)(ws + o_dstc);
    int*      bsum  = (int*)(ws + o_bsum);
    int*      boff  = (int*)(ws + o_boff);
    float*    Tm    = ws + o_T;
    float*    Mm    = ws + o_Mm;
    unsigned short* Wb = (unsigned short*)(ws + o_Wb);

    const int EB = (TE + 255) / 256;
    const int NB4  = (N + 3) / 4;
    const int NB16 = (N + 15) / 16;

    // ---- dual CSR (by dst for aggregation, by src for softmax denominator) ----
    hipMemsetAsync(degd, 0, (size_t)4 * N * 4, stream);   // degd+degs+filld+fills
    k_deg2<<<EB, 256, 0, stream>>>(ei, degd, degs);
    k_scan1<<<SCAN_B, 256, 0, stream>>>(degd, bsum);
    k_scan2<<<1, 256, 0, stream>>>(bsum, boff, rowp);
    k_scan3<<<SCAN_B, 256, 0, stream>>>(degd, boff, rowp);
    k_scan1<<<SCAN_B, 256, 0, stream>>>(degs, bsum);
    k_scan2<<<1, 256, 0, stream>>>(bsum, boff, srcp);
    k_scan3<<<SCAN_B, 256, 0, stream>>>(degs, boff, srcp);
    k_fill2<<<EB, 256, 0, stream>>>(ei, rowp, srcp, filld, fills, srcc, dstc);

    // ---- W bf16 copies (one launch) ----
    k_wb3<<<192, 256, 0, stream>>>(W[0], W[1], W[2], Wb);

    // ---- 3 GAT layers (no per-layer memsets, no atomics in softmax) ----
    for (int l = 0; l < 3; l++) {
        // gemm reads previous layer's colsum/colsq (l>0); k_den zeroes them after.
        k_gemm<<<GEMM_B, 256, 0, stream>>>(x, O16, Wb + l * 16384, Hb16, att[l],
                                           ai, ajx, csum, csq, gg[l == 0 ? 0 : l - 1],
                                           be[l == 0 ? 0 : l - 1], l > 0 ? 1 : 0);
        k_den<<<NB16, 256, 0, stream>>>(srcp, dstc, ai, ajx, csum);
        k_aggregate<<<NB4, 256, 0, stream>>>(rowp, srcc, ai, ajinv, Hu2, bb[l], O16);
        k_stats<<<256, 256, 0, stream>>>(O16, csum, csq);
    }

    // ---- decoder (BN finalize for layer 3 is inlined in k_pred) ----
    k_T<<<32, 256, 0, stream>>>(P1, P2, Tm);
    k_M<<<64, 256, 0, stream>>>(Tm, P1, Mm);
    k_pred<<<1024, 128, 0, stream>>>(O16, csum, csq, gg[2], be[2], drug, Mm, (float*)d_out);
}

// Round 2
// 434.123 us; speedup vs baseline: 1.2018x; 1.1582x over previous
//
#include <hip/hip_runtime.h>
#include <hip/hip_bf16.h>

#define DEVINL __device__ __forceinline__

constexpr int N  = 50000;
constexpr int E  = 600000;
constexpr int TE = E + N;      // edges + self loops
constexpr int D  = 128;
constexpr int SCAN_B = (N + 255) / 256;   // 196 blocks for hierarchical scan
constexpr int GEMM_ROWS = 64;             // 16 rows per wave, 4 waves
constexpr int GEMM_B = (N + GEMM_ROWS - 1) / GEMM_ROWS;  // 782
constexpr int HST_STRIDE = 136;           // ushorts; quad-staggered banks, 16B-aligned

typedef short bf16x8 __attribute__((ext_vector_type(8)));
typedef float f32x4  __attribute__((ext_vector_type(4)));

DEVINL float lrelu(float x, float s) { return x >= 0.f ? x : s * x; }

DEVINL unsigned short f2bf(float f) {   // RNE fp32 -> bf16
    unsigned u = __float_as_uint(f);
    u += 0x7FFFu + ((u >> 16) & 1u);
    return (unsigned short)(u >> 16);
}
DEVINL float bfl(unsigned u) { return __uint_as_float(u << 16); }          // low bf16
DEVINL float bfh(unsigned u) { return __uint_as_float(u & 0xFFFF0000u); }  // high bf16

// ---------- W -> bf16 copy for all 3 layers (layout unchanged: Wb[o][k]) ----------
__global__ __launch_bounds__(256) void k_wb3(const float* __restrict__ W0,
                                             const float* __restrict__ W1,
                                             const float* __restrict__ W2,
                                             unsigned short* __restrict__ Wb) {
    int b = blockIdx.x;          // 192 blocks: 64 per layer
    int l = b >> 6;
    const float* W = (l == 0) ? W0 : (l == 1) ? W1 : W2;
    int t = (b & 63) * 256 + threadIdx.x;   // 0..16383
    Wb[l * 16384 + t] = f2bf(W[t]);
}

// ---------- MFMA GEMM: H[v,o] = sum_k BN(Xin)[v,k] * W[o,k]  (bf16 in, fp32 acc) ----------
// apply_bn=0: input = fp32 X. apply_bn=1: input = bf16 O16; BN scale/shift computed
// per-block from colsum/colsq (replaces the separate k_bnfinal launch — R15).
// R16: aj is stored interleaved at ajx[2*row] (ajx[2*row+1] = invden, filled by k_den)
// so k_aggregate can gather (aj, invden) as one float2.
__global__ __launch_bounds__(256) void k_gemm(const float* __restrict__ X,
                                              const unsigned short* __restrict__ O16,
                                              const unsigned short* __restrict__ Wb,
                                              unsigned short* __restrict__ Hb16,
                                              const float* __restrict__ att,
                                              float* __restrict__ ai,
                                              float* __restrict__ ajx,
                                              const float* __restrict__ csum,
                                              const float* __restrict__ csq,
                                              const float* __restrict__ g,
                                              const float* __restrict__ be,
                                              int apply_bn) {
    __shared__ unsigned short hst[4][16][HST_STRIDE];   // ~17 KB
    __shared__ float ssl[256];                          // scale[128], shift[128]
    int wave = threadIdx.x >> 6, lane = threadIdx.x & 63;
    int m = lane & 15, quad = lane >> 4;
    int r0 = blockIdx.x * GEMM_ROWS + wave * 16;

    if (apply_bn) {
        if (threadIdx.x < 128) {
            int c = threadIdx.x;
            float mean = csum[c] / (float)N;
            float var  = csq[c] / (float)N - mean * mean;
            float scale = g[c] * rsqrtf(var + 1e-5f);
            ssl[c] = scale;
            ssl[128 + c] = be[c] - mean * scale;
        }
        __syncthreads();
    }

    // ---- A fragments for 4 K-steps ----
    bf16x8 afrag[4];
    int rowA = r0 + m;
    bool rowok = rowA < N;
    #pragma unroll
    for (int k4 = 0; k4 < 4; k4++) {
        int c0 = k4 * 32 + quad * 8;   // feature column of first element
        float v[8];
        if (rowok) {
            if (apply_bn) {
                uint4 hu = *(const uint4*)(O16 + (size_t)rowA * D + c0);
                v[0] = bfl(hu.x); v[1] = bfh(hu.x);
                v[2] = bfl(hu.y); v[3] = bfh(hu.y);
                v[4] = bfl(hu.z); v[5] = bfh(hu.z);
                v[6] = bfl(hu.w); v[7] = bfh(hu.w);
                #pragma unroll
                for (int j = 0; j < 8; j++)
                    v[j] = lrelu(v[j] * ssl[c0 + j] + ssl[128 + c0 + j], 0.1f);
            } else {
                float4 x0 = *(const float4*)(X + (size_t)rowA * D + c0);
                float4 x1 = *(const float4*)(X + (size_t)rowA * D + c0 + 4);
                v[0] = x0.x; v[1] = x0.y; v[2] = x0.z; v[3] = x0.w;
                v[4] = x1.x; v[5] = x1.y; v[6] = x1.z; v[7] = x1.w;
            }
        } else {
            #pragma unroll
            for (int j = 0; j < 8; j++) v[j] = 0.f;
        }
        #pragma unroll
        for (int j = 0; j < 8; j++) afrag[k4][j] = (short)f2bf(v[j]);
    }

    // ---- 8 col-tiles of 16, K=128 via 4 MFMA each ----
    float pii[4] = {0.f, 0.f, 0.f, 0.f};
    float pjj[4] = {0.f, 0.f, 0.f, 0.f};
    #pragma unroll
    for (int nt = 0; nt < 8; nt++) {
        int n0 = nt * 16;
        f32x4 acc = {0.f, 0.f, 0.f, 0.f};
        const unsigned short* wrow = Wb + (size_t)(n0 + m) * D + quad * 8;
        #pragma unroll
        for (int k4 = 0; k4 < 4; k4++) {
            bf16x8 b = *(const bf16x8*)(wrow + k4 * 32);
            acc = __builtin_amdgcn_mfma_f32_16x16x32_bf16(afrag[k4], b, acc, 0, 0, 0);
        }
        float ad = att[n0 + m];
        float as = att[128 + n0 + m];
        #pragma unroll
        for (int i = 0; i < 4; i++) {
            hst[wave][quad * 4 + i][n0 + m] = f2bf(acc[i]);
            pii[i] += acc[i] * ad;
            pjj[i] += acc[i] * as;
        }
    }

    // ---- coalesced H flush: lane reads 16B of a staged row, dwordx4 store ----
    #pragma unroll
    for (int t = 0; t < 4; t++) {
        int r = t * 4 + quad;              // 0..15 within wave tile
        int row = r0 + r;
        int cb = m * 8;                    // ushort col base (16 B)
        uint4 vv = *(const uint4*)&hst[wave][r][cb];
        if (row < N)
            *(uint4*)(Hb16 + (size_t)row * D + cb) = vv;
    }

    // ---- reduce attention dots across the 16 lanes of each quad ----
    #pragma unroll
    for (int mask = 8; mask >= 1; mask >>= 1) {
        #pragma unroll
        for (int i = 0; i < 4; i++) {
            pii[i] += __shfl_xor(pii[i], mask);
            pjj[i] += __shfl_xor(pjj[i], mask);
        }
    }
    if (m == 0) {
        #pragma unroll
        for (int i = 0; i < 4; i++) {
            int row = r0 + quad * 4 + i;
            if (row < N) { ai[row] = pii[i]; ajx[2 * (size_t)row] = pjj[i]; }
        }
    }
}

DEVINL void edge_sd(int e, const int* ei, int& s, int& d) {
    if (e < E) { s = ei[e]; d = ei[E + e]; }
    else       { s = d = e - E; }
}

// ---------- dual CSR build (once per run; graph shared across layers) ----------
// R17: k_deg2 keeps the atomicAdd return values as per-edge ranks (packed uint,
// coalesced store) so k_fill2 needs ZERO atomics — round-1 rocprof showed fill2's
// 1.3M far-atomics write ~42MB through to HBM (~32B each). CSR payload arrays are
// ushort (node ids < 65536) to halve scattered-store partial-line evictions.
__global__ __launch_bounds__(256) void k_deg2(const int* __restrict__ ei,
                                              int* __restrict__ degd,
                                              int* __restrict__ degs,
                                              unsigned* __restrict__ rpack) {
    int e = blockIdx.x * 256 + threadIdx.x;
    if (e >= TE) return;
    int s, d; edge_sd(e, ei, s, d);
    int rd = atomicAdd(degd + d, 1);
    int rs = atomicAdd(degs + s, 1);
    rpack[e] = (unsigned)(rd & 0xFFFF) | ((unsigned)rs << 16);
}

// scan over BOTH deg arrays in one launch: blocks [0,SCAN_B) -> degd, [SCAN_B,2*SCAN_B) -> degs
__global__ __launch_bounds__(256) void k_scan1(const int* __restrict__ degbase, int* __restrict__ bsum) {
    __shared__ int red[256];
    int arr = blockIdx.x >= SCAN_B;
    int b   = blockIdx.x - arr * SCAN_B;
    const int* deg = degbase + (size_t)arr * N;
    int t = threadIdx.x;
    int v = b * 256 + t;
    red[t] = (v < N) ? deg[v] : 0;
    __syncthreads();
    #pragma unroll
    for (int off = 128; off; off >>= 1) {
        if (t < off) red[t] += red[t + off];
        __syncthreads();
    }
    if (t == 0) bsum[arr * 256 + b] = red[0];
}

__global__ __launch_bounds__(256) void k_scan2(const int* __restrict__ bsum,
                                               int* __restrict__ boff, int* __restrict__ ptrbase) {
    __shared__ int sc[256];
    int t = threadIdx.x;
    for (int arr = 0; arr < 2; arr++) {
        int v = (t < SCAN_B) ? bsum[arr * 256 + t] : 0;
        sc[t] = v;
        __syncthreads();
        #pragma unroll
        for (int off = 1; off < 256; off <<= 1) {
            int add = (t >= off) ? sc[t - off] : 0;
            __syncthreads();
            sc[t] += add;
            __syncthreads();
        }
        if (t < SCAN_B) boff[arr * 256 + t] = sc[t] - v;       // exclusive
        if (t == SCAN_B - 1) ptrbase[(size_t)arr * (N + 8) + N] = sc[t];   // total = TE
        __syncthreads();   // sc reused next iteration
    }
}

__global__ __launch_bounds__(256) void k_scan3(const int* __restrict__ degbase,
                                               const int* __restrict__ boff,
                                               int* __restrict__ ptrbase) {
    __shared__ int sc[256];
    int arr = blockIdx.x >= SCAN_B;
    int b   = blockIdx.x - arr * SCAN_B;
    const int* deg = degbase + (size_t)arr * N;
    int* ptr       = ptrbase + (size_t)arr * (N + 8);
    int t = threadIdx.x;
    int v = b * 256 + t;
    int d = (v < N) ? deg[v] : 0;
    sc[t] = d;
    __syncthreads();
    #pragma unroll
    for (int off = 1; off < 256; off <<= 1) {
        int add = (t >= off) ? sc[t - off] : 0;
        __syncthreads();
        sc[t] += add;
        __syncthreads();
    }
    if (v < N) ptr[v] = boff[arr * 256 + b] + sc[t] - d;
}

// ---------- fill both CSRs in one edge pass: NO atomics, ushort payload ----------
__global__ __launch_bounds__(256) void k_fill2(const int* __restrict__ ei,
                                               const int* __restrict__ rowp,
                                               const int* __restrict__ srcp,
                                               const unsigned* __restrict__ rpack,
                                               unsigned short* __restrict__ srcc,
                                               unsigned short* __restrict__ dstc) {
    int e = blockIdx.x * 256 + threadIdx.x;
    if (e >= TE) return;
    int s, d; edge_sd(e, ei, s, d);
    unsigned rp = rpack[e];
    srcc[rowp[d] + (int)(rp & 0xFFFFu)] = (unsigned short)s;
    dstc[srcp[s] + (int)(rp >> 16)]     = (unsigned short)d;
}

// ---------- softmax denominator: 16-lane group per SRC node, no atomics ----------
// den[s] = sum over out-edges (s->d) of exp(lrelu(ai[d] + aj[s])); store 1/den
// interleaved next to aj so the aggregate gather is a single float2.
// Block 0 also zeroes colsum/colsq (256 floats) for this layer's k_stats —
// safe: runs after k_gemm consumed the previous layer's stats (stream order).
__global__ __launch_bounds__(256) void k_den(const int* __restrict__ srcp,
                                             const unsigned short* __restrict__ dstc,
                                             const float* __restrict__ ai,
                                             float* __restrict__ ajx,
                                             float* __restrict__ csumz) {
    if (blockIdx.x == 0) csumz[threadIdx.x] = 0.f;
    int g = threadIdx.x >> 4, l16 = threadIdx.x & 15;
    int v = blockIdx.x * 16 + g;
    if (v >= N) return;
    int beg = srcp[v], end = srcp[v + 1];
    float ajv = ajx[2 * (size_t)v];
    float acc = 0.f;
    for (int idx = beg + l16; idx < end; idx += 16) {
        int d = dstc[idx];
        acc += expf(lrelu(ai[d] + ajv, 0.2f));
    }
    #pragma unroll
    for (int mask = 8; mask >= 1; mask >>= 1) acc += __shfl_xor(acc, mask);
    if (l16 == 0) ajx[2 * (size_t)v + 1] = 1.0f / (acc + 1e-16f);
}

// ---------- aggregation: wave per dst node, pair-gather, bf16 O output ----------
// (R9 NOTE: no per-slot clamping in the hot loop — predication before gathers kills MLP.)
// R16: weights computed on the fly: w = exp(lrelu(ai[v]+aj[s])) * invden[s].
// (aj,invden) is one float2 gather; alpha array + k_edge_soft eliminated.
__global__ __launch_bounds__(256) void k_aggregate(const int* __restrict__ rowp,
                                                   const unsigned short* __restrict__ srcc,
                                                   const float* __restrict__ ai,
                                                   const float2* __restrict__ ajinv,
                                                   const uint2* __restrict__ Hu2, // 4 bf16 per uint2
                                                   const float* __restrict__ bvec,
                                                   unsigned short* __restrict__ O16) {
    int wid = threadIdx.x >> 6, lane = threadIdx.x & 63;
    int h = lane >> 5, l32 = lane & 31;
    int v = blockIdx.x * 4 + wid;
    if (v >= N) return;
    int beg = rowp[v], end = rowp[v + 1];   // non-empty (self loop)
    float aiv = ai[v];
    float a0 = 0.f, a1 = 0.f, a2 = 0.f, a3 = 0.f;
    int idx = beg;
    for (; idx + 8 <= end; idx += 8) {            // 4 pairs = 8 edges
        int    s[4];
        float2 aw[4];
        uint2  u[4];
        #pragma unroll
        for (int t = 0; t < 4; t++) s[t] = srcc[idx + 2 * t + h];
        #pragma unroll
        for (int t = 0; t < 4; t++) aw[t] = ajinv[s[t]];
        #pragma unroll
        for (int t = 0; t < 4; t++) u[t] = Hu2[(size_t)s[t] * 32 + l32];
        #pragma unroll
        for (int t = 0; t < 4; t++) {
            float w = expf(lrelu(aiv + aw[t].x, 0.2f)) * aw[t].y;
            a0 += w * bfl(u[t].x);
            a1 += w * bfh(u[t].x);
            a2 += w * bfl(u[t].y);
            a3 += w * bfh(u[t].y);
        }
    }
    for (; idx + 2 <= end; idx += 2) {            // pair tail
        int s = srcc[idx + h];
        float2 aw = ajinv[s];
        float w = expf(lrelu(aiv + aw.x, 0.2f)) * aw.y;
        uint2 u = Hu2[(size_t)s * 32 + l32];
        a0 += w * bfl(u.x);
        a1 += w * bfh(u.x);
        a2 += w * bfl(u.y);
        a3 += w * bfh(u.y);
    }
    if (idx < end) {                              // single tail: half 1 weight 0
        int s = srcc[idx];
        float2 aw = ajinv[s];
        float w = (h == 0) ? expf(lrelu(aiv + aw.x, 0.2f)) * aw.y : 0.f;
        uint2 u = Hu2[(size_t)s * 32 + l32];
        a0 += w * bfl(u.x);
        a1 += w * bfh(u.x);
        a2 += w * bfl(u.y);
        a3 += w * bfh(u.y);
    }
    a0 += __shfl_xor(a0, 32);
    a1 += __shfl_xor(a1, 32);
    a2 += __shfl_xor(a2, 32);
    a3 += __shfl_xor(a3, 32);
    if (h == 0) {
        float4 b = ((const float4*)bvec)[l32];
        float o0 = fmaxf(a0 + b.x, 0.f);
        float o1 = fmaxf(a1 + b.y, 0.f);
        float o2 = fmaxf(a2 + b.z, 0.f);
        float o3 = fmaxf(a3 + b.w, 0.f);
        uint2 st;
        st.x = (unsigned)f2bf(o0) | ((unsigned)f2bf(o1) << 16);
        st.y = (unsigned)f2bf(o2) | ((unsigned)f2bf(o3) << 16);
        *(uint2*)(O16 + (size_t)v * D + l32 * 4) = st;
    }
}

// ---------- BN column stats on bf16 O: uint2 per thread (4 cols), LDS reduce ----------
// NOTE (R11): last-block finalize via __threadfence() cost ~35 us/layer on gfx950
// (device-scope fence = per-XCD L2 writeback per block). Finalize lives in consumers.
__global__ __launch_bounds__(256) void k_stats(const unsigned short* __restrict__ O16,
                                               float* __restrict__ colsum, float* __restrict__ colsq) {
    int c4 = (threadIdx.x & 31) * 4;   // column base (4 cols per thread)
    int rg = threadIdx.x >> 5;         // row group 0..7
    float s0=0.f,s1=0.f,s2=0.f,s3=0.f,q0=0.f,q1=0.f,q2=0.f,q3=0.f;
    for (int v = blockIdx.x * 8 + rg; v < N; v += gridDim.x * 8) {
        uint2 u = *(const uint2*)(O16 + (size_t)v * D + c4);
        float v0 = bfl(u.x), v1 = bfh(u.x), v2 = bfl(u.y), v3 = bfh(u.y);
        s0 += v0; q0 += v0 * v0;
        s1 += v1; q1 += v1 * v1;
        s2 += v2; q2 += v2 * v2;
        s3 += v3; q3 += v3 * v3;
    }
    __shared__ float ls[8][128], lq[8][128];   // 8 KB
    ls[rg][c4+0]=s0; ls[rg][c4+1]=s1; ls[rg][c4+2]=s2; ls[rg][c4+3]=s3;
    lq[rg][c4+0]=q0; lq[rg][c4+1]=q1; lq[rg][c4+2]=q2; lq[rg][c4+3]=q3;
    __syncthreads();
    if (threadIdx.x < 128) {
        int c = threadIdx.x;
        float s = 0.f, q = 0.f;
        #pragma unroll
        for (int r = 0; r < 8; r++) { s += ls[r][c]; q += lq[r][c]; }
        atomicAdd(colsum + c, s);
        atomicAdd(colsq + c, q);
    }
}

// ---------- decoder ----------
__global__ __launch_bounds__(256) void k_T(const float* __restrict__ P1, const float* __restrict__ P2,
                                           float* __restrict__ T) {
    int t = blockIdx.x * 256 + threadIdx.x;
    if (t >= 128 * 64) return;
    int i = t >> 6, d = t & 63;
    float s = 0.f;
    #pragma unroll 8
    for (int k = 0; k < 64; k++) s += P1[i * 64 + k] * P2[k * 64 + d];
    T[t] = s;
}

__global__ __launch_bounds__(256) void k_M(const float* __restrict__ T, const float* __restrict__ P1,
                                           float* __restrict__ M) {
    int t = blockIdx.x * 256 + threadIdx.x;
    if (t >= 128 * 128) return;
    int i = t >> 7, j = t & 127;
    float s = 0.f;
    #pragma unroll 8
    for (int d = 0; d < 64; d++) s += T[i * 64 + d] * P1[j * 64 + d];
    M[t] = s;
}

__global__ __launch_bounds__(128) void k_pred(const unsigned short* __restrict__ O16,
                                              const float* __restrict__ csum,
                                              const float* __restrict__ csq,
                                              const float* __restrict__ g,
                                              const float* __restrict__ be,
                                              const int* __restrict__ drug,
                                              const float* __restrict__ M,
                                              float* __restrict__ out) {
    int b = blockIdx.x, i = threadIdx.x;
    __shared__ float av[128], bv[128];
    int ia = drug[b * 2] - 1, ib = drug[b * 2 + 1] - 1;
    float mean = csum[i] / (float)N;
    float var  = csq[i] / (float)N - mean * mean;
    float scale = g[i] * rsqrtf(var + 1e-5f);
    float shift = be[i] - mean * scale;
    float ha = __uint_as_float(((unsigned)O16[(size_t)ia * D + i]) << 16);
    float hb = __uint_as_float(((unsigned)O16[(size_t)ib * D + i]) << 16);
    av[i] = lrelu(ha * scale + shift, 0.1f);
    bv[i] = lrelu(hb * scale + shift, 0.1f);
    __syncthreads();
    const float4* M4  = (const float4*)(M + (size_t)i * 128);
    const float4* bv4 = (const float4*)bv;
    float u = 0.f;
    #pragma unroll 8
    for (int j = 0; j < 32; j++) {
        float4 mv = M4[j];
        float4 bb = bv4[j];
        u += mv.x * bb.x + mv.y * bb.y + mv.z * bb.z + mv.w * bb.w;
    }
    float val = av[i] * u;
    #pragma unroll
    for (int off = 32; off; off >>= 1) val += __shfl_down(val, off);
    __shared__ float red[2];
    if ((i & 63) == 0) red[i >> 6] = val;
    __syncthreads();
    if (i == 0) out[b] = red[0] + red[1];
}

extern "C" void kernel_launch(void* const* d_in, const int* in_sizes, int n_in,
                              void* d_out, int out_size, void* d_ws, size_t ws_size,
                              hipStream_t stream) {
    const float* x    = (const float*)d_in[0];
    const int*   ei   = (const int*)  d_in[1];
    const int*   drug = (const int*)  d_in[2];
    const float* W[3]   = {(const float*)d_in[3], (const float*)d_in[8],  (const float*)d_in[13]};
    const float* att[3] = {(const float*)d_in[4], (const float*)d_in[9],  (const float*)d_in[14]};
    const float* bb[3]  = {(const float*)d_in[5], (const float*)d_in[10], (const float*)d_in[15]};
    const float* gg[3]  = {(const float*)d_in[6], (const float*)d_in[11], (const float*)d_in[16]};
    const float* be[3]  = {(const float*)d_in[7], (const float*)d_in[12], (const float*)d_in[17]};
    const float* P1 = (const float*)d_in[18];
    const float* P2 = (const float*)d_in[19];

    float* ws = (float*)d_ws;
    size_t o_H      = 0;                     // bf16 H: N*128 ushorts = N*64 float slots
    size_t o_O      = o_H + (size_t)N * 64;  // bf16 O: N*128 ushorts = N*64 float slots
    size_t o_ai     = o_O + (size_t)N * 64;
    size_t o_ajinv  = o_ai + N;              // float2 per node: (aj, invden)
    size_t o_colsum = o_ajinv + 2 * (size_t)N;  // 128
    size_t o_colsq  = o_colsum + 128;           // 128
    size_t o_deg    = o_colsq + 128;   // ints: degd[N] degs[N]  (contiguous for fused scans)
    size_t o_rpack  = o_deg + 2 * (size_t)N;    // uint, TE (per-edge packed ranks)
    size_t o_rowptr = o_rpack + TE;             // int, N+8 (rowp) then N+8 (srcp) contiguous
    size_t o_srcp   = o_rowptr + N + 8;
    size_t o_src    = o_srcp + N + 8;  // ushort, TE  (src per dst-CSR slot) -> TE/2+1 float slots
    size_t o_dstc   = o_src + TE / 2 + 8;  // ushort, TE (dst per src-CSR slot)
    size_t o_bsum   = o_dstc + TE / 2 + 8; // int, 2*256
    size_t o_boff   = o_bsum + 512;    // int, 2*256
    size_t o_T      = o_boff + 512;    // 128*64
    size_t o_Mm     = o_T + 128 * 64;  // 128*128
    size_t o_Wb     = o_Mm + 128 * 128;// 3*16384 ushorts = 24576 floats

    unsigned short* Hb16 = (unsigned short*)(ws + o_H);
    uint2*          Hu2  = (uint2*)(ws + o_H);
    unsigned short* O16  = (unsigned short*)(ws + o_O);
    float*    ai    = ws + o_ai;
    float*    ajx   = ws + o_ajinv;
    float2*   ajinv = (float2*)(ws + o_ajinv);
    float*    csum  = ws + o_colsum;
    float*    csq   = ws + o_colsq;
    int*      degd  = (int*)(ws + o_deg);
    int*      degs  = degd + N;
    unsigned* rpack = (unsigned*)(ws + o_rpack);
    int*      rowp  = (int*)(ws + o_rowptr);
    int*      srcp  = (int*)(ws + o_srcp);
    unsigned short* srcc = (unsigned short*)(ws + o_src);
    unsigned short* dstc = (unsigned short*)(ws + o_dstc);
    int*      bsum  = (int*)(ws + o_bsum);
    int*      boff  = (int*)(ws + o_boff);
    float*    Tm    = ws + o_T;
    float*    Mm    = ws + o_Mm;
    unsigned short* Wb = (unsigned short*)(ws + o_Wb);

    const int EB = (TE + 255) / 256;
    const int NB4  = (N + 3) / 4;
    const int NB16 = (N + 15) / 16;

    // ---- dual CSR (by dst for aggregation, by src for softmax denominator) ----
    hipMemsetAsync(degd, 0, (size_t)2 * N * 4, stream);   // degd+degs
    k_deg2<<<EB, 256, 0, stream>>>(ei, degd, degs, rpack);
    k_scan1<<<2 * SCAN_B, 256, 0, stream>>>(degd, bsum);
    k_scan2<<<1, 256, 0, stream>>>(bsum, boff, rowp);   // rowp base; srcp = rowp + (N+8)
    k_scan3<<<2 * SCAN_B, 256, 0, stream>>>(degd, boff, rowp);
    k_fill2<<<EB, 256, 0, stream>>>(ei, rowp, srcp, rpack, srcc, dstc);

    // ---- W bf16 copies (one launch) ----
    k_wb3<<<192, 256, 0, stream>>>(W[0], W[1], W[2], Wb);

    // ---- 3 GAT layers (no per-layer memsets, no atomics in softmax) ----
    for (int l = 0; l < 3; l++) {
        // gemm reads previous layer's colsum/colsq (l>0); k_den zeroes them after.
        k_gemm<<<GEMM_B, 256, 0, stream>>>(x, O16, Wb + l * 16384, Hb16, att[l],
                                           ai, ajx, csum, csq, gg[l == 0 ? 0 : l - 1],
                                           be[l == 0 ? 0 : l - 1], l > 0 ? 1 : 0);
        k_den<<<NB16, 256, 0, stream>>>(srcp, dstc, ai, ajx, csum);
        k_aggregate<<<NB4, 256, 0, stream>>>(rowp, srcc, ai, ajinv, Hu2, bb[l], O16);
        k_stats<<<256, 256, 0, stream>>>(O16, csum, csq);
    }

    // ---- decoder (BN finalize for layer 3 is inlined in k_pred) ----
    k_T<<<32, 256, 0, stream>>>(P1, P2, Tm);
    k_M<<<64, 256, 0, stream>>>(Tm, P1, Mm);
    k_pred<<<1024, 128, 0, stream>>>(O16, csum, csq, gg[2], be[2], drug, Mm, (float*)d_out);
}

// Round 3
// 432.424 us; speedup vs baseline: 1.2066x; 1.0039x over previous
//
#include <hip/hip_runtime.h>
#include <hip/hip_bf16.h>

#define DEVINL __device__ __forceinline__

constexpr int N  = 50000;
constexpr int E  = 600000;
constexpr int TE = E + N;      // edges + self loops
constexpr int D  = 128;
constexpr int NXCD = 8;                   // MI355X XCD count (s_getreg XCC_ID in 0..7)
constexpr int SCAN_B = (N + 255) / 256;   // 196 blocks for hierarchical scan
constexpr int GEMM_ROWS = 64;             // 16 rows per wave, 4 waves
constexpr int GEMM_B = (N + GEMM_ROWS - 1) / GEMM_ROWS;  // 782
constexpr int HST_STRIDE = 136;           // ushorts; quad-staggered banks, 16B-aligned

typedef short bf16x8 __attribute__((ext_vector_type(8)));
typedef float f32x4  __attribute__((ext_vector_type(4)));

DEVINL float lrelu(float x, float s) { return x >= 0.f ? x : s * x; }

DEVINL unsigned short f2bf(float f) {   // RNE fp32 -> bf16
    unsigned u = __float_as_uint(f);
    u += 0x7FFFu + ((u >> 16) & 1u);
    return (unsigned short)(u >> 16);
}
DEVINL float bfl(unsigned u) { return __uint_as_float(u << 16); }          // low bf16
DEVINL float bfh(unsigned u) { return __uint_as_float(u & 0xFFFF0000u); }  // high bf16

// ---------- W -> bf16 copy for all 3 layers (layout unchanged: Wb[o][k]) ----------
__global__ __launch_bounds__(256) void k_wb3(const float* __restrict__ W0,
                                             const float* __restrict__ W1,
                                             const float* __restrict__ W2,
                                             unsigned short* __restrict__ Wb) {
    int b = blockIdx.x;          // 192 blocks: 64 per layer
    int l = b >> 6;
    const float* W = (l == 0) ? W0 : (l == 1) ? W1 : W2;
    int t = (b & 63) * 256 + threadIdx.x;   // 0..16383
    Wb[l * 16384 + t] = f2bf(W[t]);
}

// ---------- MFMA GEMM: H[v,o] = sum_k BN(Xin)[v,k] * W[o,k]  (bf16 in, fp32 acc) ----------
// apply_bn=0: input = fp32 X. apply_bn=1: input = bf16 O16; BN scale/shift computed
// per-block from colsum/colsq (replaces the separate k_bnfinal launch — R15).
// R16: aj is stored interleaved at ajx[2*row] (ajx[2*row+1] = invden, filled by k_den)
// so k_aggregate can gather (aj, invden) as one float2.
__global__ __launch_bounds__(256) void k_gemm(const float* __restrict__ X,
                                              const unsigned short* __restrict__ O16,
                                              const unsigned short* __restrict__ Wb,
                                              unsigned short* __restrict__ Hb16,
                                              const float* __restrict__ att,
                                              float* __restrict__ ai,
                                              float* __restrict__ ajx,
                                              const float* __restrict__ csum,
                                              const float* __restrict__ csq,
                                              const float* __restrict__ g,
                                              const float* __restrict__ be,
                                              int apply_bn) {
    __shared__ unsigned short hst[4][16][HST_STRIDE];   // ~17 KB
    __shared__ float ssl[256];                          // scale[128], shift[128]
    int wave = threadIdx.x >> 6, lane = threadIdx.x & 63;
    int m = lane & 15, quad = lane >> 4;
    int r0 = blockIdx.x * GEMM_ROWS + wave * 16;

    if (apply_bn) {
        if (threadIdx.x < 128) {
            int c = threadIdx.x;
            float mean = csum[c] / (float)N;
            float var  = csq[c] / (float)N - mean * mean;
            float scale = g[c] * rsqrtf(var + 1e-5f);
            ssl[c] = scale;
            ssl[128 + c] = be[c] - mean * scale;
        }
        __syncthreads();
    }

    // ---- A fragments for 4 K-steps ----
    bf16x8 afrag[4];
    int rowA = r0 + m;
    bool rowok = rowA < N;
    #pragma unroll
    for (int k4 = 0; k4 < 4; k4++) {
        int c0 = k4 * 32 + quad * 8;   // feature column of first element
        float v[8];
        if (rowok) {
            if (apply_bn) {
                uint4 hu = *(const uint4*)(O16 + (size_t)rowA * D + c0);
                v[0] = bfl(hu.x); v[1] = bfh(hu.x);
                v[2] = bfl(hu.y); v[3] = bfh(hu.y);
                v[4] = bfl(hu.z); v[5] = bfh(hu.z);
                v[6] = bfl(hu.w); v[7] = bfh(hu.w);
                #pragma unroll
                for (int j = 0; j < 8; j++)
                    v[j] = lrelu(v[j] * ssl[c0 + j] + ssl[128 + c0 + j], 0.1f);
            } else {
                float4 x0 = *(const float4*)(X + (size_t)rowA * D + c0);
                float4 x1 = *(const float4*)(X + (size_t)rowA * D + c0 + 4);
                v[0] = x0.x; v[1] = x0.y; v[2] = x0.z; v[3] = x0.w;
                v[4] = x1.x; v[5] = x1.y; v[6] = x1.z; v[7] = x1.w;
            }
        } else {
            #pragma unroll
            for (int j = 0; j < 8; j++) v[j] = 0.f;
        }
        #pragma unroll
        for (int j = 0; j < 8; j++) afrag[k4][j] = (short)f2bf(v[j]);
    }

    // ---- 8 col-tiles of 16, K=128 via 4 MFMA each ----
    float pii[4] = {0.f, 0.f, 0.f, 0.f};
    float pjj[4] = {0.f, 0.f, 0.f, 0.f};
    #pragma unroll
    for (int nt = 0; nt < 8; nt++) {
        int n0 = nt * 16;
        f32x4 acc = {0.f, 0.f, 0.f, 0.f};
        const unsigned short* wrow = Wb + (size_t)(n0 + m) * D + quad * 8;
        #pragma unroll
        for (int k4 = 0; k4 < 4; k4++) {
            bf16x8 b = *(const bf16x8*)(wrow + k4 * 32);
            acc = __builtin_amdgcn_mfma_f32_16x16x32_bf16(afrag[k4], b, acc, 0, 0, 0);
        }
        float ad = att[n0 + m];
        float as = att[128 + n0 + m];
        #pragma unroll
        for (int i = 0; i < 4; i++) {
            hst[wave][quad * 4 + i][n0 + m] = f2bf(acc[i]);
            pii[i] += acc[i] * ad;
            pjj[i] += acc[i] * as;
        }
    }

    // ---- coalesced H flush: lane reads 16B of a staged row, dwordx4 store ----
    #pragma unroll
    for (int t = 0; t < 4; t++) {
        int r = t * 4 + quad;              // 0..15 within wave tile
        int row = r0 + r;
        int cb = m * 8;                    // ushort col base (16 B)
        uint4 vv = *(const uint4*)&hst[wave][r][cb];
        if (row < N)
            *(uint4*)(Hb16 + (size_t)row * D + cb) = vv;
    }

    // ---- reduce attention dots across the 16 lanes of each quad ----
    #pragma unroll
    for (int mask = 8; mask >= 1; mask >>= 1) {
        #pragma unroll
        for (int i = 0; i < 4; i++) {
            pii[i] += __shfl_xor(pii[i], mask);
            pjj[i] += __shfl_xor(pjj[i], mask);
        }
    }
    if (m == 0) {
        #pragma unroll
        for (int i = 0; i < 4; i++) {
            int row = r0 + quad * 4 + i;
            if (row < N) { ai[row] = pii[i]; ajx[2 * (size_t)row] = pjj[i]; }
        }
    }
}

DEVINL void edge_sd(int e, const int* ei, int& s, int& d) {
    if (e < E) { s = ei[e]; d = ei[E + e]; }
    else       { s = d = e - E; }
}

// ---------- dual CSR build (once per run; graph shared across layers) ----------
// R18: agent-scope atomics on gfx950 execute at the far coherent point and dirty
// one 32B HBM sector each (~1 TB/s ceiling; measured 3x: R0 k_edge_soft, R1
// k_fill2, R2 k_deg2 = 40MB write for 1.3M atomics). Fix: per-XCD partial
// histograms updated with WORKGROUP-scope atomics -> global_atomic_add sc0
// (no sc1) executes in the LOCAL TCC, cached write-back. All updaters of copy x
// are on XCD x (runtime s_getreg XCC_ID), so XCD-local atomicity suffices;
// visibility comes from the dispatch-end L2 writeback every kernel already
// relies on. Ranks compose as cumx[xcd][v] (exclusive xcd-prefix, from k_scan1)
// + local rank. rpack = rd:13 | rs:13 | xcd:3 (max degree ~40 << 8191).
__global__ __launch_bounds__(256) void k_deg2(const int* __restrict__ ei,
                                              int* __restrict__ part,   // [2][NXCD][N]
                                              unsigned* __restrict__ rpack) {
    int e = blockIdx.x * 256 + threadIdx.x;
    if (e >= TE) return;
    unsigned xcd;
    asm volatile("s_getreg_b32 %0, hwreg(HW_REG_XCC_ID)" : "=s"(xcd));
    xcd &= (NXCD - 1);
    int s, d; edge_sd(e, ei, s, d);
    int rd = __hip_atomic_fetch_add(part + ((size_t)xcd * N + d), 1,
                                    __ATOMIC_RELAXED, __HIP_MEMORY_SCOPE_WORKGROUP);
    int rs = __hip_atomic_fetch_add(part + (((size_t)NXCD + xcd) * N + s), 1,
                                    __ATOMIC_RELAXED, __HIP_MEMORY_SCOPE_WORKGROUP);
    rpack[e] = (unsigned)rd | ((unsigned)rs << 13) | (xcd << 26);
}

// scan1 (fused): sum the 8 per-XCD partials -> deg, emit exclusive xcd-prefix
// cumx (ushort), then the usual per-block total. blocks [0,SCAN_B)=dst side,
// [SCAN_B,2*SCAN_B)=src side.
__global__ __launch_bounds__(256) void k_scan1(const int* __restrict__ part,
                                               int* __restrict__ deg,            // [2][N]
                                               unsigned short* __restrict__ cumx,// [2][NXCD][N]
                                               int* __restrict__ bsum) {
    __shared__ int red[256];
    int arr = blockIdx.x >= SCAN_B;
    int b   = blockIdx.x - arr * SCAN_B;
    int t = threadIdx.x;
    int v = b * 256 + t;
    int run = 0;
    if (v < N) {
        #pragma unroll
        for (int x = 0; x < NXCD; x++) {
            size_t o = ((size_t)arr * NXCD + x) * N + v;
            cumx[o] = (unsigned short)run;
            run += part[o];
        }
        deg[(size_t)arr * N + v] = run;
    }
    red[t] = run;
    __syncthreads();
    #pragma unroll
    for (int off = 128; off; off >>= 1) {
        if (t < off) red[t] += red[t + off];
        __syncthreads();
    }
    if (t == 0) bsum[arr * 256 + b] = red[0];
}

__global__ __launch_bounds__(256) void k_scan2(const int* __restrict__ bsum,
                                               int* __restrict__ boff, int* __restrict__ ptrbase) {
    __shared__ int sc[256];
    int t = threadIdx.x;
    for (int arr = 0; arr < 2; arr++) {
        int v = (t < SCAN_B) ? bsum[arr * 256 + t] : 0;
        sc[t] = v;
        __syncthreads();
        #pragma unroll
        for (int off = 1; off < 256; off <<= 1) {
            int add = (t >= off) ? sc[t - off] : 0;
            __syncthreads();
            sc[t] += add;
            __syncthreads();
        }
        if (t < SCAN_B) boff[arr * 256 + t] = sc[t] - v;       // exclusive
        if (t == SCAN_B - 1) ptrbase[(size_t)arr * (N + 8) + N] = sc[t];   // total = TE
        __syncthreads();   // sc reused next iteration
    }
}

__global__ __launch_bounds__(256) void k_scan3(const int* __restrict__ degbase,
                                               const int* __restrict__ boff,
                                               int* __restrict__ ptrbase) {
    __shared__ int sc[256];
    int arr = blockIdx.x >= SCAN_B;
    int b   = blockIdx.x - arr * SCAN_B;
    const int* deg = degbase + (size_t)arr * N;
    int* ptr       = ptrbase + (size_t)arr * (N + 8);
    int t = threadIdx.x;
    int v = b * 256 + t;
    int d = (v < N) ? deg[v] : 0;
    sc[t] = d;
    __syncthreads();
    #pragma unroll
    for (int off = 1; off < 256; off <<= 1) {
        int add = (t >= off) ? sc[t - off] : 0;
        __syncthreads();
        sc[t] += add;
        __syncthreads();
    }
    if (v < N) ptr[v] = boff[arr * 256 + b] + sc[t] - d;
}

// ---------- fill both CSRs in one edge pass: NO atomics, ushort payload ----------
__global__ __launch_bounds__(256) void k_fill2(const int* __restrict__ ei,
                                               const int* __restrict__ rowp,
                                               const int* __restrict__ srcp,
                                               const unsigned* __restrict__ rpack,
                                               const unsigned short* __restrict__ cumx,
                                               unsigned short* __restrict__ srcc,
                                               unsigned short* __restrict__ dstc) {
    int e = blockIdx.x * 256 + threadIdx.x;
    if (e >= TE) return;
    int s, d; edge_sd(e, ei, s, d);
    unsigned rp = rpack[e];
    int rd  = (int)(rp & 0x1FFFu);
    int rs  = (int)((rp >> 13) & 0x1FFFu);
    int xcd = (int)(rp >> 26);
    int posd = rowp[d] + (int)cumx[(size_t)xcd * N + d] + rd;
    int poss = srcp[s] + (int)cumx[((size_t)NXCD + xcd) * N + s] + rs;
    srcc[posd] = (unsigned short)s;
    dstc[poss] = (unsigned short)d;
}

// ---------- softmax denominator: 16-lane group per SRC node, no atomics ----------
// den[s] = sum over out-edges (s->d) of exp(lrelu(ai[d] + aj[s])); store 1/den
// interleaved next to aj so the aggregate gather is a single float2.
// Block 0 also zeroes colsum/colsq (256 floats) for this layer's k_stats —
// safe: runs after k_gemm consumed the previous layer's stats (stream order).
__global__ __launch_bounds__(256) void k_den(const int* __restrict__ srcp,
                                             const unsigned short* __restrict__ dstc,
                                             const float* __restrict__ ai,
                                             float* __restrict__ ajx,
                                             float* __restrict__ csumz) {
    if (blockIdx.x == 0) csumz[threadIdx.x] = 0.f;
    int g = threadIdx.x >> 4, l16 = threadIdx.x & 15;
    int v = blockIdx.x * 16 + g;
    if (v >= N) return;
    int beg = srcp[v], end = srcp[v + 1];
    float ajv = ajx[2 * (size_t)v];
    float acc = 0.f;
    for (int idx = beg + l16; idx < end; idx += 16) {
        int d = dstc[idx];
        acc += expf(lrelu(ai[d] + ajv, 0.2f));
    }
    #pragma unroll
    for (int mask = 8; mask >= 1; mask >>= 1) acc += __shfl_xor(acc, mask);
    if (l16 == 0) ajx[2 * (size_t)v + 1] = 1.0f / (acc + 1e-16f);
}

// ---------- aggregation: wave per dst node, pair-gather, bf16 O output ----------
// (R9 NOTE: no per-slot clamping in the hot loop — predication before gathers kills MLP.)
// R16: weights computed on the fly: w = exp(lrelu(ai[v]+aj[s])) * invden[s].
// (aj,invden) is one float2 gather; alpha array + k_edge_soft eliminated.
__global__ __launch_bounds__(256) void k_aggregate(const int* __restrict__ rowp,
                                                   const unsigned short* __restrict__ srcc,
                                                   const float* __restrict__ ai,
                                                   const float2* __restrict__ ajinv,
                                                   const uint2* __restrict__ Hu2, // 4 bf16 per uint2
                                                   const float* __restrict__ bvec,
                                                   unsigned short* __restrict__ O16) {
    int wid = threadIdx.x >> 6, lane = threadIdx.x & 63;
    int h = lane >> 5, l32 = lane & 31;
    int v = blockIdx.x * 4 + wid;
    if (v >= N) return;
    int beg = rowp[v], end = rowp[v + 1];   // non-empty (self loop)
    float aiv = ai[v];
    float a0 = 0.f, a1 = 0.f, a2 = 0.f, a3 = 0.f;
    int idx = beg;
    for (; idx + 8 <= end; idx += 8) {            // 4 pairs = 8 edges
        int    s[4];
        float2 aw[4];
        uint2  u[4];
        #pragma unroll
        for (int t = 0; t < 4; t++) s[t] = srcc[idx + 2 * t + h];
        #pragma unroll
        for (int t = 0; t < 4; t++) aw[t] = ajinv[s[t]];
        #pragma unroll
        for (int t = 0; t < 4; t++) u[t] = Hu2[(size_t)s[t] * 32 + l32];
        #pragma unroll
        for (int t = 0; t < 4; t++) {
            float w = expf(lrelu(aiv + aw[t].x, 0.2f)) * aw[t].y;
            a0 += w * bfl(u[t].x);
            a1 += w * bfh(u[t].x);
            a2 += w * bfl(u[t].y);
            a3 += w * bfh(u[t].y);
        }
    }
    for (; idx + 2 <= end; idx += 2) {            // pair tail
        int s = srcc[idx + h];
        float2 aw = ajinv[s];
        float w = expf(lrelu(aiv + aw.x, 0.2f)) * aw.y;
        uint2 u = Hu2[(size_t)s * 32 + l32];
        a0 += w * bfl(u.x);
        a1 += w * bfh(u.x);
        a2 += w * bfl(u.y);
        a3 += w * bfh(u.y);
    }
    if (idx < end) {                              // single tail: half 1 weight 0
        int s = srcc[idx];
        float2 aw = ajinv[s];
        float w = (h == 0) ? expf(lrelu(aiv + aw.x, 0.2f)) * aw.y : 0.f;
        uint2 u = Hu2[(size_t)s * 32 + l32];
        a0 += w * bfl(u.x);
        a1 += w * bfh(u.x);
        a2 += w * bfl(u.y);
        a3 += w * bfh(u.y);
    }
    a0 += __shfl_xor(a0, 32);
    a1 += __shfl_xor(a1, 32);
    a2 += __shfl_xor(a2, 32);
    a3 += __shfl_xor(a3, 32);
    if (h == 0) {
        float4 b = ((const float4*)bvec)[l32];
        float o0 = fmaxf(a0 + b.x, 0.f);
        float o1 = fmaxf(a1 + b.y, 0.f);
        float o2 = fmaxf(a2 + b.z, 0.f);
        float o3 = fmaxf(a3 + b.w, 0.f);
        uint2 st;
        st.x = (unsigned)f2bf(o0) | ((unsigned)f2bf(o1) << 16);
        st.y = (unsigned)f2bf(o2) | ((unsigned)f2bf(o3) << 16);
        *(uint2*)(O16 + (size_t)v * D + l32 * 4) = st;
    }
}

// ---------- BN column stats on bf16 O: uint2 per thread (4 cols), LDS reduce ----------
// NOTE (R11): last-block finalize via __threadfence() cost ~35 us/layer on gfx950
// (device-scope fence = per-XCD L2 writeback per block). Finalize lives in consumers.
__global__ __launch_bounds__(256) void k_stats(const unsigned short* __restrict__ O16,
                                               float* __restrict__ colsum, float* __restrict__ colsq) {
    int c4 = (threadIdx.x & 31) * 4;   // column base (4 cols per thread)
    int rg = threadIdx.x >> 5;         // row group 0..7
    float s0=0.f,s1=0.f,s2=0.f,s3=0.f,q0=0.f,q1=0.f,q2=0.f,q3=0.f;
    for (int v = blockIdx.x * 8 + rg; v < N; v += gridDim.x * 8) {
        uint2 u = *(const uint2*)(O16 + (size_t)v * D + c4);
        float v0 = bfl(u.x), v1 = bfh(u.x), v2 = bfl(u.y), v3 = bfh(u.y);
        s0 += v0; q0 += v0 * v0;
        s1 += v1; q1 += v1 * v1;
        s2 += v2; q2 += v2 * v2;
        s3 += v3; q3 += v3 * v3;
    }
    __shared__ float ls[8][128], lq[8][128];   // 8 KB
    ls[rg][c4+0]=s0; ls[rg][c4+1]=s1; ls[rg][c4+2]=s2; ls[rg][c4+3]=s3;
    lq[rg][c4+0]=q0; lq[rg][c4+1]=q1; lq[rg][c4+2]=q2; lq[rg][c4+3]=q3;
    __syncthreads();
    if (threadIdx.x < 128) {
        int c = threadIdx.x;
        float s = 0.f, q = 0.f;
        #pragma unroll
        for (int r = 0; r < 8; r++) { s += ls[r][c]; q += lq[r][c]; }
        atomicAdd(colsum + c, s);
        atomicAdd(colsq + c, q);
    }
}

// ---------- decoder ----------
__global__ __launch_bounds__(256) void k_T(const float* __restrict__ P1, const float* __restrict__ P2,
                                           float* __restrict__ T) {
    int t = blockIdx.x * 256 + threadIdx.x;
    if (t >= 128 * 64) return;
    int i = t >> 6, d = t & 63;
    float s = 0.f;
    #pragma unroll 8
    for (int k = 0; k < 64; k++) s += P1[i * 64 + k] * P2[k * 64 + d];
    T[t] = s;
}

__global__ __launch_bounds__(256) void k_M(const float* __restrict__ T, const float* __restrict__ P1,
                                           float* __restrict__ M) {
    int t = blockIdx.x * 256 + threadIdx.x;
    if (t >= 128 * 128) return;
    int i = t >> 7, j = t & 127;
    float s = 0.f;
    #pragma unroll 8
    for (int d = 0; d < 64; d++) s += T[i * 64 + d] * P1[j * 64 + d];
    M[t] = s;
}

__global__ __launch_bounds__(128) void k_pred(const unsigned short* __restrict__ O16,
                                              const float* __restrict__ csum,
                                              const float* __restrict__ csq,
                                              const float* __restrict__ g,
                                              const float* __restrict__ be,
                                              const int* __restrict__ drug,
                                              const float* __restrict__ M,
                                              float* __restrict__ out) {
    int b = blockIdx.x, i = threadIdx.x;
    __shared__ float av[128], bv[128];
    int ia = drug[b * 2] - 1, ib = drug[b * 2 + 1] - 1;
    float mean = csum[i] / (float)N;
    float var  = csq[i] / (float)N - mean * mean;
    float scale = g[i] * rsqrtf(var + 1e-5f);
    float shift = be[i] - mean * scale;
    float ha = __uint_as_float(((unsigned)O16[(size_t)ia * D + i]) << 16);
    float hb = __uint_as_float(((unsigned)O16[(size_t)ib * D + i]) << 16);
    av[i] = lrelu(ha * scale + shift, 0.1f);
    bv[i] = lrelu(hb * scale + shift, 0.1f);
    __syncthreads();
    const float4* M4  = (const float4*)(M + (size_t)i * 128);
    const float4* bv4 = (const float4*)bv;
    float u = 0.f;
    #pragma unroll 8
    for (int j = 0; j < 32; j++) {
        float4 mv = M4[j];
        float4 bb = bv4[j];
        u += mv.x * bb.x + mv.y * bb.y + mv.z * bb.z + mv.w * bb.w;
    }
    float val = av[i] * u;
    #pragma unroll
    for (int off = 32; off; off >>= 1) val += __shfl_down(val, off);
    __shared__ float red[2];
    if ((i & 63) == 0) red[i >> 6] = val;
    __syncthreads();
    if (i == 0) out[b] = red[0] + red[1];
}

extern "C" void kernel_launch(void* const* d_in, const int* in_sizes, int n_in,
                              void* d_out, int out_size, void* d_ws, size_t ws_size,
                              hipStream_t stream) {
    const float* x    = (const float*)d_in[0];
    const int*   ei   = (const int*)  d_in[1];
    const int*   drug = (const int*)  d_in[2];
    const float* W[3]   = {(const float*)d_in[3], (const float*)d_in[8],  (const float*)d_in[13]};
    const float* att[3] = {(const float*)d_in[4], (const float*)d_in[9],  (const float*)d_in[14]};
    const float* bb[3]  = {(const float*)d_in[5], (const float*)d_in[10], (const float*)d_in[15]};
    const float* gg[3]  = {(const float*)d_in[6], (const float*)d_in[11], (const float*)d_in[16]};
    const float* be[3]  = {(const float*)d_in[7], (const float*)d_in[12], (const float*)d_in[17]};
    const float* P1 = (const float*)d_in[18];
    const float* P2 = (const float*)d_in[19];

    float* ws = (float*)d_ws;
    size_t o_H      = 0;                     // bf16 H: N*128 ushorts = N*64 float slots
    size_t o_O      = o_H + (size_t)N * 64;  // bf16 O: N*128 ushorts = N*64 float slots
    size_t o_ai     = o_O + (size_t)N * 64;
    size_t o_ajinv  = o_ai + N;              // float2 per node: (aj, invden)
    size_t o_colsum = o_ajinv + 2 * (size_t)N;  // 128
    size_t o_colsq  = o_colsum + 128;           // 128
    size_t o_part   = o_colsq + 128;            // int [2][NXCD][N] per-XCD partial hist
    size_t o_deg    = o_part + 2 * NXCD * (size_t)N;  // int [2][N]
    size_t o_cumx   = o_deg + 2 * (size_t)N;    // ushort [2][NXCD][N] -> NXCD*N float slots
    size_t o_rpack  = o_cumx + NXCD * (size_t)N;// uint, TE (per-edge packed ranks+xcd)
    size_t o_rowptr = o_rpack + TE;             // int, N+8 (rowp) then N+8 (srcp) contiguous
    size_t o_srcp   = o_rowptr + N + 8;
    size_t o_src    = o_srcp + N + 8;  // ushort, TE  (src per dst-CSR slot)
    size_t o_dstc   = o_src + TE / 2 + 8;  // ushort, TE (dst per src-CSR slot)
    size_t o_bsum   = o_dstc + TE / 2 + 8; // int, 2*256
    size_t o_boff   = o_bsum + 512;    // int, 2*256
    size_t o_T      = o_boff + 512;    // 128*64
    size_t o_Mm     = o_T + 128 * 64;  // 128*128
    size_t o_Wb     = o_Mm + 128 * 128;// 3*16384 ushorts = 24576 floats

    unsigned short* Hb16 = (unsigned short*)(ws + o_H);
    uint2*          Hu2  = (uint2*)(ws + o_H);
    unsigned short* O16  = (unsigned short*)(ws + o_O);
    float*    ai    = ws + o_ai;
    float*    ajx   = ws + o_ajinv;
    float2*   ajinv = (float2*)(ws + o_ajinv);
    float*    csum  = ws + o_colsum;
    float*    csq   = ws + o_colsq;
    int*      part  = (int*)(ws + o_part);
    int*      deg   = (int*)(ws + o_deg);
    unsigned short* cumx = (unsigned short*)(ws + o_cumx);
    unsigned* rpack = (unsigned*)(ws + o_rpack);
    int*      rowp  = (int*)(ws + o_rowptr);
    int*      srcp  = (int*)(ws + o_srcp);
    unsigned short* srcc = (unsigned short*)(ws + o_src);
    unsigned short* dstc = (unsigned short*)(ws + o_dstc);
    int*      bsum  = (int*)(ws + o_bsum);
    int*      boff  = (int*)(ws + o_boff);
    float*    Tm    = ws + o_T;
    float*    Mm    = ws + o_Mm;
    unsigned short* Wb = (unsigned short*)(ws + o_Wb);

    const int EB = (TE + 255) / 256;
    const int NB4  = (N + 3) / 4;
    const int NB16 = (N + 15) / 16;

    // ---- dual CSR (by dst for aggregation, by src for softmax denominator) ----
    hipMemsetAsync(part, 0, (size_t)2 * NXCD * N * 4, stream);
    k_deg2<<<EB, 256, 0, stream>>>(ei, part, rpack);
    k_scan1<<<2 * SCAN_B, 256, 0, stream>>>(part, deg, cumx, bsum);
    k_scan2<<<1, 256, 0, stream>>>(bsum, boff, rowp);   // rowp base; srcp = rowp + (N+8)
    k_scan3<<<2 * SCAN_B, 256, 0, stream>>>(deg, boff, rowp);
    k_fill2<<<EB, 256, 0, stream>>>(ei, rowp, srcp, rpack, cumx, srcc, dstc);

    // ---- W bf16 copies (one launch) ----
    k_wb3<<<192, 256, 0, stream>>>(W[0], W[1], W[2], Wb);

    // ---- 3 GAT layers (no per-layer memsets, no atomics in softmax) ----
    for (int l = 0; l < 3; l++) {
        // gemm reads previous layer's colsum/colsq (l>0); k_den zeroes them after.
        k_gemm<<<GEMM_B, 256, 0, stream>>>(x, O16, Wb + l * 16384, Hb16, att[l],
                                           ai, ajx, csum, csq, gg[l == 0 ? 0 : l - 1],
                                           be[l == 0 ? 0 : l - 1], l > 0 ? 1 : 0);
        k_den<<<NB16, 256, 0, stream>>>(srcp, dstc, ai, ajx, csum);
        k_aggregate<<<NB4, 256, 0, stream>>>(rowp, srcc, ai, ajinv, Hu2, bb[l], O16);
        k_stats<<<256, 256, 0, stream>>>(O16, csum, csq);
    }

    // ---- decoder (BN finalize for layer 3 is inlined in k_pred) ----
    k_T<<<32, 256, 0, stream>>>(P1, P2, Tm);
    k_M<<<64, 256, 0, stream>>>(Tm, P1, Mm);
    k_pred<<<1024, 128, 0, stream>>>(O16, csum, csq, gg[2], be[2], drug, Mm, (float*)d_out);
}

// Round 4
// 389.113 us; speedup vs baseline: 1.3409x; 1.1113x over previous
//
#include <hip/hip_runtime.h>
#include <hip/hip_bf16.h>

#define DEVINL __device__ __forceinline__

constexpr int N  = 50000;
constexpr int E  = 600000;
constexpr int TE = E + N;      // edges + self loops
constexpr int D  = 128;
constexpr int GEMM_ROWS = 64;             // 16 rows per wave, 4 waves
constexpr int GEMM_B = (N + GEMM_ROWS - 1) / GEMM_ROWS;  // 782
constexpr int HST_STRIDE = 136;           // ushorts; quad-staggered banks, 16B-aligned

// ---- counting-sort CSR build params (R19) ----
constexpr int NBUCK = (N + 255) >> 8;     // 196 buckets of 256 nodes
constexpr int NSB   = 2 * NBUCK;          // both sides (dst-keyed, src-keyed)
constexpr int CHUNK = 2560;               // edges per count/scatter block
constexpr int EB3   = (TE + CHUNK - 1) / CHUNK;  // 254 (must be <= 256 for 1-block scan)
constexpr int EB3P  = 256;                // padded stride for pref rows

typedef short bf16x8 __attribute__((ext_vector_type(8)));
typedef float f32x4  __attribute__((ext_vector_type(4)));

DEVINL float lrelu(float x, float s) { return x >= 0.f ? x : s * x; }

DEVINL unsigned short f2bf(float f) {   // RNE fp32 -> bf16
    unsigned u = __float_as_uint(f);
    u += 0x7FFFu + ((u >> 16) & 1u);
    return (unsigned short)(u >> 16);
}
DEVINL float bfl(unsigned u) { return __uint_as_float(u << 16); }          // low bf16
DEVINL float bfh(unsigned u) { return __uint_as_float(u & 0xFFFF0000u); }  // high bf16

// ---------- W -> bf16 copy for all 3 layers (layout unchanged: Wb[o][k]) ----------
__global__ __launch_bounds__(256) void k_wb3(const float* __restrict__ W0,
                                             const float* __restrict__ W1,
                                             const float* __restrict__ W2,
                                             unsigned short* __restrict__ Wb) {
    int b = blockIdx.x;          // 192 blocks: 64 per layer
    int l = b >> 6;
    const float* W = (l == 0) ? W0 : (l == 1) ? W1 : W2;
    int t = (b & 63) * 256 + threadIdx.x;   // 0..16383
    Wb[l * 16384 + t] = f2bf(W[t]);
}

// ---------- MFMA GEMM: H[v,o] = sum_k BN(Xin)[v,k] * W[o,k]  (bf16 in, fp32 acc) ----------
__global__ __launch_bounds__(256) void k_gemm(const float* __restrict__ X,
                                              const unsigned short* __restrict__ O16,
                                              const unsigned short* __restrict__ Wb,
                                              unsigned short* __restrict__ Hb16,
                                              const float* __restrict__ att,
                                              float* __restrict__ ai,
                                              float* __restrict__ ajx,
                                              const float* __restrict__ csum,
                                              const float* __restrict__ csq,
                                              const float* __restrict__ g,
                                              const float* __restrict__ be,
                                              int apply_bn) {
    __shared__ unsigned short hst[4][16][HST_STRIDE];   // ~17 KB
    __shared__ float ssl[256];                          // scale[128], shift[128]
    int wave = threadIdx.x >> 6, lane = threadIdx.x & 63;
    int m = lane & 15, quad = lane >> 4;
    int r0 = blockIdx.x * GEMM_ROWS + wave * 16;

    if (apply_bn) {
        if (threadIdx.x < 128) {
            int c = threadIdx.x;
            float mean = csum[c] / (float)N;
            float var  = csq[c] / (float)N - mean * mean;
            float scale = g[c] * rsqrtf(var + 1e-5f);
            ssl[c] = scale;
            ssl[128 + c] = be[c] - mean * scale;
        }
        __syncthreads();
    }

    // ---- A fragments for 4 K-steps ----
    bf16x8 afrag[4];
    int rowA = r0 + m;
    bool rowok = rowA < N;
    #pragma unroll
    for (int k4 = 0; k4 < 4; k4++) {
        int c0 = k4 * 32 + quad * 8;   // feature column of first element
        float v[8];
        if (rowok) {
            if (apply_bn) {
                uint4 hu = *(const uint4*)(O16 + (size_t)rowA * D + c0);
                v[0] = bfl(hu.x); v[1] = bfh(hu.x);
                v[2] = bfl(hu.y); v[3] = bfh(hu.y);
                v[4] = bfl(hu.z); v[5] = bfh(hu.z);
                v[6] = bfl(hu.w); v[7] = bfh(hu.w);
                #pragma unroll
                for (int j = 0; j < 8; j++)
                    v[j] = lrelu(v[j] * ssl[c0 + j] + ssl[128 + c0 + j], 0.1f);
            } else {
                float4 x0 = *(const float4*)(X + (size_t)rowA * D + c0);
                float4 x1 = *(const float4*)(X + (size_t)rowA * D + c0 + 4);
                v[0] = x0.x; v[1] = x0.y; v[2] = x0.z; v[3] = x0.w;
                v[4] = x1.x; v[5] = x1.y; v[6] = x1.z; v[7] = x1.w;
            }
        } else {
            #pragma unroll
            for (int j = 0; j < 8; j++) v[j] = 0.f;
        }
        #pragma unroll
        for (int j = 0; j < 8; j++) afrag[k4][j] = (short)f2bf(v[j]);
    }

    // ---- 8 col-tiles of 16, K=128 via 4 MFMA each ----
    float pii[4] = {0.f, 0.f, 0.f, 0.f};
    float pjj[4] = {0.f, 0.f, 0.f, 0.f};
    #pragma unroll
    for (int nt = 0; nt < 8; nt++) {
        int n0 = nt * 16;
        f32x4 acc = {0.f, 0.f, 0.f, 0.f};
        const unsigned short* wrow = Wb + (size_t)(n0 + m) * D + quad * 8;
        #pragma unroll
        for (int k4 = 0; k4 < 4; k4++) {
            bf16x8 b = *(const bf16x8*)(wrow + k4 * 32);
            acc = __builtin_amdgcn_mfma_f32_16x16x32_bf16(afrag[k4], b, acc, 0, 0, 0);
        }
        float ad = att[n0 + m];
        float as = att[128 + n0 + m];
        #pragma unroll
        for (int i = 0; i < 4; i++) {
            hst[wave][quad * 4 + i][n0 + m] = f2bf(acc[i]);
            pii[i] += acc[i] * ad;
            pjj[i] += acc[i] * as;
        }
    }

    // ---- coalesced H flush: lane reads 16B of a staged row, dwordx4 store ----
    #pragma unroll
    for (int t = 0; t < 4; t++) {
        int r = t * 4 + quad;              // 0..15 within wave tile
        int row = r0 + r;
        int cb = m * 8;                    // ushort col base (16 B)
        uint4 vv = *(const uint4*)&hst[wave][r][cb];
        if (row < N)
            *(uint4*)(Hb16 + (size_t)row * D + cb) = vv;
    }

    // ---- reduce attention dots across the 16 lanes of each quad ----
    #pragma unroll
    for (int mask = 8; mask >= 1; mask >>= 1) {
        #pragma unroll
        for (int i = 0; i < 4; i++) {
            pii[i] += __shfl_xor(pii[i], mask);
            pjj[i] += __shfl_xor(pjj[i], mask);
        }
    }
    if (m == 0) {
        #pragma unroll
        for (int i = 0; i < 4; i++) {
            int row = r0 + quad * 4 + i;
            if (row < N) { ai[row] = pii[i]; ajx[2 * (size_t)row] = pjj[i]; }
        }
    }
}

DEVINL void edge_sd(int e, const int* ei, int& s, int& d) {
    if (e < E) { s = ei[e]; d = ei[E + e]; }
    else       { s = d = e - E; }
}

// ---------- CSR build via 2-level counting sort (R19) ----------
// R18 post-mortem: global atomic RMWs on gfx950 write ~32B through to HBM
// REGARDLESS of requested memory scope (measured 4x: edge_soft/fill2/deg2x2,
// all ~32B/atomic, ~1 TB/s). Scoped atomics are NOT a fix. So the build now
// uses ONLY LDS atomics (no HBM write-through) and block-contiguous global
// writes:
//   k_cnt:     per-block LDS histogram over 392 (side,bucket) counters,
//              bucket = node>>8; one coalesced row store per block.
//   k_bscan:   exclusive scan of per-block counts per (side,bucket).
//   k_boff:    scan bucket totals per side -> bucket bases; rowp[N]/srcp[N].
//   k_scatter: slot via LDS alloc[bucket]++ (block's slots per bucket are
//              CONTIGUOUS -> write-combining works, unlike random 2B scatter).
//              sorted word = (node&255)<<16 | payload.
//   k_csr:     block = bucket: LDS count -> scan -> rowp, then LDS-alloc
//              placement of ushort payload into the bucket's contiguous region.
__global__ __launch_bounds__(256) void k_cnt(const int* __restrict__ ei,
                                             unsigned* __restrict__ hist) {  // [EB3][NSB]
    __shared__ unsigned cnt[NSB];
    for (int t = threadIdx.x; t < NSB; t += 256) cnt[t] = 0;
    __syncthreads();
    int base = blockIdx.x * CHUNK;
    for (int i = threadIdx.x; i < CHUNK; i += 256) {
        int e = base + i;
        if (e < TE) {
            int s, d; edge_sd(e, ei, s, d);
            atomicAdd(&cnt[d >> 8], 1u);
            atomicAdd(&cnt[NBUCK + (s >> 8)], 1u);
        }
    }
    __syncthreads();
    unsigned* row = hist + (size_t)blockIdx.x * NSB;
    for (int t = threadIdx.x; t < NSB; t += 256) row[t] = cnt[t];
}

__global__ __launch_bounds__(256) void k_bscan(const unsigned* __restrict__ hist,
                                               unsigned* __restrict__ pref,   // [NSB][EB3P]
                                               unsigned* __restrict__ btot) { // [NSB]
    __shared__ unsigned sc[256];
    int sb = blockIdx.x, t = threadIdx.x;
    unsigned v = (t < EB3) ? hist[(size_t)t * NSB + sb] : 0;
    sc[t] = v;
    __syncthreads();
    #pragma unroll
    for (int off = 1; off < 256; off <<= 1) {
        unsigned add = (t >= off) ? sc[t - off] : 0;
        __syncthreads();
        sc[t] += add;
        __syncthreads();
    }
    if (t < EB3) pref[(size_t)sb * EB3P + t] = sc[t] - v;   // exclusive
    if (t == EB3 - 1) btot[sb] = sc[t];
}

__global__ __launch_bounds__(256) void k_boff(const unsigned* __restrict__ btot,
                                              unsigned* __restrict__ boff2,   // [2][NBUCK+1]
                                              int* __restrict__ ptrbase) {
    __shared__ unsigned sc[256];
    int t = threadIdx.x;
    for (int side = 0; side < 2; side++) {
        unsigned v = (t < NBUCK) ? btot[side * NBUCK + t] : 0;
        sc[t] = v;
        __syncthreads();
        #pragma unroll
        for (int off = 1; off < 256; off <<= 1) {
            unsigned add = (t >= off) ? sc[t - off] : 0;
            __syncthreads();
            sc[t] += add;
            __syncthreads();
        }
        if (t < NBUCK) boff2[side * (NBUCK + 1) + t] = sc[t] - v;  // exclusive
        if (t == NBUCK - 1) boff2[side * (NBUCK + 1) + NBUCK] = sc[t];  // = TE
        __syncthreads();
    }
    if (t == 0) { ptrbase[N] = TE; ptrbase[(N + 8) + N] = TE; }
}

__global__ __launch_bounds__(256) void k_scatter(const int* __restrict__ ei,
                                                 const unsigned* __restrict__ pref,
                                                 const unsigned* __restrict__ boff2,
                                                 unsigned* __restrict__ sorted) { // [2*TE]
    __shared__ unsigned alloc[NSB];
    int j = blockIdx.x;
    for (int t = threadIdx.x; t < NSB; t += 256) {
        int side = t >= NBUCK;
        int bucket = t - side * NBUCK;
        alloc[t] = boff2[side * (NBUCK + 1) + bucket] + pref[(size_t)t * EB3P + j]
                 + (side ? (unsigned)TE : 0u);   // side-1 half lives at sorted+TE
    }
    __syncthreads();
    int base = j * CHUNK;
    for (int i = threadIdx.x; i < CHUNK; i += 256) {
        int e = base + i;
        if (e < TE) {
            int s, d; edge_sd(e, ei, s, d);
            unsigned pd = atomicAdd(&alloc[d >> 8], 1u);
            sorted[pd] = ((unsigned)(d & 255) << 16) | (unsigned)s;
            unsigned ps = atomicAdd(&alloc[NBUCK + (s >> 8)], 1u);
            sorted[ps] = ((unsigned)(s & 255) << 16) | (unsigned)d;
        }
    }
}

__global__ __launch_bounds__(256) void k_csr(const unsigned* __restrict__ sorted,
                                             const unsigned* __restrict__ boff2,
                                             int* __restrict__ ptrbase,
                                             unsigned short* __restrict__ srcc,
                                             unsigned short* __restrict__ dstc) {
    __shared__ unsigned cnt[256];
    __shared__ unsigned sc[256];
    int sb = blockIdx.x, t = threadIdx.x;
    int side = sb >= NBUCK;
    int bucket = sb - side * NBUCK;
    unsigned beg = boff2[side * (NBUCK + 1) + bucket];
    unsigned end = boff2[side * (NBUCK + 1) + bucket + 1];
    const unsigned* srt = sorted + (side ? (size_t)TE : 0);
    unsigned short* out = side ? dstc : srcc;
    int* ptr = ptrbase + (size_t)side * (N + 8);
    cnt[t] = 0;
    __syncthreads();
    for (unsigned idx = beg + t; idx < end; idx += 256)
        atomicAdd(&cnt[srt[idx] >> 16], 1u);
    __syncthreads();
    unsigned own = cnt[t];
    sc[t] = own;
    __syncthreads();
    #pragma unroll
    for (int off = 1; off < 256; off <<= 1) {
        unsigned add = (t >= off) ? sc[t - off] : 0;
        __syncthreads();
        sc[t] += add;
        __syncthreads();
    }
    unsigned loc = sc[t] - own;           // exclusive within bucket
    int v = (bucket << 8) + t;
    if (v < N) ptr[v] = (int)(beg + loc);
    cnt[t] = beg + loc;                   // reuse as allocator
    __syncthreads();
    for (unsigned idx = beg + t; idx < end; idx += 256) {
        unsigned u = srt[idx];
        unsigned pos = atomicAdd(&cnt[u >> 16], 1u);
        out[pos] = (unsigned short)u;
    }
}

// ---------- softmax denominator: 16-lane group per SRC node, no atomics ----------
// den[s] = sum over out-edges (s->d) of exp(lrelu(ai[d] + aj[s])); store 1/den
// interleaved next to aj so the aggregate gather is a single float2.
// Block 0 also zeroes colsum/colsq (256 floats) for this layer's k_stats —
// safe: runs after k_gemm consumed the previous layer's stats (stream order).
__global__ __launch_bounds__(256) void k_den(const int* __restrict__ srcp,
                                             const unsigned short* __restrict__ dstc,
                                             const float* __restrict__ ai,
                                             float* __restrict__ ajx,
                                             float* __restrict__ csumz) {
    if (blockIdx.x == 0) csumz[threadIdx.x] = 0.f;
    int g = threadIdx.x >> 4, l16 = threadIdx.x & 15;
    int v = blockIdx.x * 16 + g;
    if (v >= N) return;
    int beg = srcp[v], end = srcp[v + 1];
    float ajv = ajx[2 * (size_t)v];
    float acc = 0.f;
    for (int idx = beg + l16; idx < end; idx += 16) {
        int d = dstc[idx];
        acc += expf(lrelu(ai[d] + ajv, 0.2f));
    }
    #pragma unroll
    for (int mask = 8; mask >= 1; mask >>= 1) acc += __shfl_xor(acc, mask);
    if (l16 == 0) ajx[2 * (size_t)v + 1] = 1.0f / (acc + 1e-16f);
}

// ---------- aggregation: wave per dst node, pair-gather, bf16 O output ----------
__global__ __launch_bounds__(256) void k_aggregate(const int* __restrict__ rowp,
                                                   const unsigned short* __restrict__ srcc,
                                                   const float* __restrict__ ai,
                                                   const float2* __restrict__ ajinv,
                                                   const uint2* __restrict__ Hu2, // 4 bf16 per uint2
                                                   const float* __restrict__ bvec,
                                                   unsigned short* __restrict__ O16) {
    int wid = threadIdx.x >> 6, lane = threadIdx.x & 63;
    int h = lane >> 5, l32 = lane & 31;
    int v = blockIdx.x * 4 + wid;
    if (v >= N) return;
    int beg = rowp[v], end = rowp[v + 1];   // non-empty (self loop)
    float aiv = ai[v];
    float a0 = 0.f, a1 = 0.f, a2 = 0.f, a3 = 0.f;
    int idx = beg;
    for (; idx + 8 <= end; idx += 8) {            // 4 pairs = 8 edges
        int    s[4];
        float2 aw[4];
        uint2  u[4];
        #pragma unroll
        for (int t = 0; t < 4; t++) s[t] = srcc[idx + 2 * t + h];
        #pragma unroll
        for (int t = 0; t < 4; t++) aw[t] = ajinv[s[t]];
        #pragma unroll
        for (int t = 0; t < 4; t++) u[t] = Hu2[(size_t)s[t] * 32 + l32];
        #pragma unroll
        for (int t = 0; t < 4; t++) {
            float w = expf(lrelu(aiv + aw[t].x, 0.2f)) * aw[t].y;
            a0 += w * bfl(u[t].x);
            a1 += w * bfh(u[t].x);
            a2 += w * bfl(u[t].y);
            a3 += w * bfh(u[t].y);
        }
    }
    for (; idx + 2 <= end; idx += 2) {            // pair tail
        int s = srcc[idx + h];
        float2 aw = ajinv[s];
        float w = expf(lrelu(aiv + aw.x, 0.2f)) * aw.y;
        uint2 u = Hu2[(size_t)s * 32 + l32];
        a0 += w * bfl(u.x);
        a1 += w * bfh(u.x);
        a2 += w * bfl(u.y);
        a3 += w * bfh(u.y);
    }
    if (idx < end) {                              // single tail: half 1 weight 0
        int s = srcc[idx];
        float2 aw = ajinv[s];
        float w = (h == 0) ? expf(lrelu(aiv + aw.x, 0.2f)) * aw.y : 0.f;
        uint2 u = Hu2[(size_t)s * 32 + l32];
        a0 += w * bfl(u.x);
        a1 += w * bfh(u.x);
        a2 += w * bfl(u.y);
        a3 += w * bfh(u.y);
    }
    a0 += __shfl_xor(a0, 32);
    a1 += __shfl_xor(a1, 32);
    a2 += __shfl_xor(a2, 32);
    a3 += __shfl_xor(a3, 32);
    if (h == 0) {
        float4 b = ((const float4*)bvec)[l32];
        float o0 = fmaxf(a0 + b.x, 0.f);
        float o1 = fmaxf(a1 + b.y, 0.f);
        float o2 = fmaxf(a2 + b.z, 0.f);
        float o3 = fmaxf(a3 + b.w, 0.f);
        uint2 st;
        st.x = (unsigned)f2bf(o0) | ((unsigned)f2bf(o1) << 16);
        st.y = (unsigned)f2bf(o2) | ((unsigned)f2bf(o3) << 16);
        *(uint2*)(O16 + (size_t)v * D + l32 * 4) = st;
    }
}

// ---------- BN column stats on bf16 O: uint2 per thread (4 cols), LDS reduce ----------
// NOTE (R11): last-block finalize via __threadfence() cost ~35 us/layer on gfx950
// (device-scope fence = per-XCD L2 writeback per block). Finalize lives in consumers.
__global__ __launch_bounds__(256) void k_stats(const unsigned short* __restrict__ O16,
                                               float* __restrict__ colsum, float* __restrict__ colsq) {
    int c4 = (threadIdx.x & 31) * 4;   // column base (4 cols per thread)
    int rg = threadIdx.x >> 5;         // row group 0..7
    float s0=0.f,s1=0.f,s2=0.f,s3=0.f,q0=0.f,q1=0.f,q2=0.f,q3=0.f;
    for (int v = blockIdx.x * 8 + rg; v < N; v += gridDim.x * 8) {
        uint2 u = *(const uint2*)(O16 + (size_t)v * D + c4);
        float v0 = bfl(u.x), v1 = bfh(u.x), v2 = bfl(u.y), v3 = bfh(u.y);
        s0 += v0; q0 += v0 * v0;
        s1 += v1; q1 += v1 * v1;
        s2 += v2; q2 += v2 * v2;
        s3 += v3; q3 += v3 * v3;
    }
    __shared__ float ls[8][128], lq[8][128];   // 8 KB
    ls[rg][c4+0]=s0; ls[rg][c4+1]=s1; ls[rg][c4+2]=s2; ls[rg][c4+3]=s3;
    lq[rg][c4+0]=q0; lq[rg][c4+1]=q1; lq[rg][c4+2]=q2; lq[rg][c4+3]=q3;
    __syncthreads();
    if (threadIdx.x < 128) {
        int c = threadIdx.x;
        float s = 0.f, q = 0.f;
        #pragma unroll
        for (int r = 0; r < 8; r++) { s += ls[r][c]; q += lq[r][c]; }
        atomicAdd(colsum + c, s);
        atomicAdd(colsq + c, q);
    }
}

// ---------- decoder ----------
__global__ __launch_bounds__(256) void k_T(const float* __restrict__ P1, const float* __restrict__ P2,
                                           float* __restrict__ T) {
    int t = blockIdx.x * 256 + threadIdx.x;
    if (t >= 128 * 64) return;
    int i = t >> 6, d = t & 63;
    float s = 0.f;
    #pragma unroll 8
    for (int k = 0; k < 64; k++) s += P1[i * 64 + k] * P2[k * 64 + d];
    T[t] = s;
}

__global__ __launch_bounds__(256) void k_M(const float* __restrict__ T, const float* __restrict__ P1,
                                           float* __restrict__ M) {
    int t = blockIdx.x * 256 + threadIdx.x;
    if (t >= 128 * 128) return;
    int i = t >> 7, j = t & 127;
    float s = 0.f;
    #pragma unroll 8
    for (int d = 0; d < 64; d++) s += T[i * 64 + d] * P1[j * 64 + d];
    M[t] = s;
}

__global__ __launch_bounds__(128) void k_pred(const unsigned short* __restrict__ O16,
                                              const float* __restrict__ csum,
                                              const float* __restrict__ csq,
                                              const float* __restrict__ g,
                                              const float* __restrict__ be,
                                              const int* __restrict__ drug,
                                              const float* __restrict__ M,
                                              float* __restrict__ out) {
    int b = blockIdx.x, i = threadIdx.x;
    __shared__ float av[128], bv[128];
    int ia = drug[b * 2] - 1, ib = drug[b * 2 + 1] - 1;
    float mean = csum[i] / (float)N;
    float var  = csq[i] / (float)N - mean * mean;
    float scale = g[i] * rsqrtf(var + 1e-5f);
    float shift = be[i] - mean * scale;
    float ha = __uint_as_float(((unsigned)O16[(size_t)ia * D + i]) << 16);
    float hb = __uint_as_float(((unsigned)O16[(size_t)ib * D + i]) << 16);
    av[i] = lrelu(ha * scale + shift, 0.1f);
    bv[i] = lrelu(hb * scale + shift, 0.1f);
    __syncthreads();
    const float4* M4  = (const float4*)(M + (size_t)i * 128);
    const float4* bv4 = (const float4*)bv;
    float u = 0.f;
    #pragma unroll 8
    for (int j = 0; j < 32; j++) {
        float4 mv = M4[j];
        float4 bb = bv4[j];
        u += mv.x * bb.x + mv.y * bb.y + mv.z * bb.z + mv.w * bb.w;
    }
    float val = av[i] * u;
    #pragma unroll
    for (int off = 32; off; off >>= 1) val += __shfl_down(val, off);
    __shared__ float red[2];
    if ((i & 63) == 0) red[i >> 6] = val;
    __syncthreads();
    if (i == 0) out[b] = red[0] + red[1];
}

extern "C" void kernel_launch(void* const* d_in, const int* in_sizes, int n_in,
                              void* d_out, int out_size, void* d_ws, size_t ws_size,
                              hipStream_t stream) {
    const float* x    = (const float*)d_in[0];
    const int*   ei   = (const int*)  d_in[1];
    const int*   drug = (const int*)  d_in[2];
    const float* W[3]   = {(const float*)d_in[3], (const float*)d_in[8],  (const float*)d_in[13]};
    const float* att[3] = {(const float*)d_in[4], (const float*)d_in[9],  (const float*)d_in[14]};
    const float* bb[3]  = {(const float*)d_in[5], (const float*)d_in[10], (const float*)d_in[15]};
    const float* gg[3]  = {(const float*)d_in[6], (const float*)d_in[11], (const float*)d_in[16]};
    const float* be[3]  = {(const float*)d_in[7], (const float*)d_in[12], (const float*)d_in[17]};
    const float* P1 = (const float*)d_in[18];
    const float* P2 = (const float*)d_in[19];

    float* ws = (float*)d_ws;
    size_t o_H      = 0;                     // bf16 H: N*128 ushorts = N*64 float slots
    size_t o_O      = o_H + (size_t)N * 64;  // bf16 O: N*128 ushorts = N*64 float slots
    size_t o_ai     = o_O + (size_t)N * 64;
    size_t o_ajinv  = o_ai + N;              // float2 per node: (aj, invden)
    size_t o_colsum = o_ajinv + 2 * (size_t)N;  // 128
    size_t o_colsq  = o_colsum + 128;           // 128
    size_t o_hist   = o_colsq + 128;            // uint [EB3][NSB]
    size_t o_pref   = o_hist + (size_t)EB3 * NSB;     // uint [NSB][EB3P]
    size_t o_btot   = o_pref + (size_t)NSB * EB3P;    // uint [NSB] (pad 512)
    size_t o_boff2  = o_btot + 512;                   // uint [2][NBUCK+1] (pad 512)
    size_t o_sorted = o_boff2 + 512;                  // uint [2*TE]
    size_t o_rowptr = o_sorted + 2 * (size_t)TE;      // int, N+8 (rowp) then srcp contiguous
    size_t o_srcp   = o_rowptr + N + 8;
    size_t o_src    = o_srcp + N + 8;  // ushort, TE  (src per dst-CSR slot)
    size_t o_dstc   = o_src + TE / 2 + 8;  // ushort, TE (dst per src-CSR slot)
    size_t o_T      = o_dstc + TE / 2 + 8; // 128*64
    size_t o_Mm     = o_T + 128 * 64;  // 128*128
    size_t o_Wb     = o_Mm + 128 * 128;// 3*16384 ushorts = 24576 floats

    unsigned short* Hb16 = (unsigned short*)(ws + o_H);
    uint2*          Hu2  = (uint2*)(ws + o_H);
    unsigned short* O16  = (unsigned short*)(ws + o_O);
    float*    ai    = ws + o_ai;
    float*    ajx   = ws + o_ajinv;
    float2*   ajinv = (float2*)(ws + o_ajinv);
    float*    csum  = ws + o_colsum;
    float*    csq   = ws + o_colsq;
    unsigned* hist  = (unsigned*)(ws + o_hist);
    unsigned* pref  = (unsigned*)(ws + o_pref);
    unsigned* btot  = (unsigned*)(ws + o_btot);
    unsigned* boff2 = (unsigned*)(ws + o_boff2);
    unsigned* sorted= (unsigned*)(ws + o_sorted);
    int*      rowp  = (int*)(ws + o_rowptr);
    int*      srcp  = (int*)(ws + o_srcp);
    unsigned short* srcc = (unsigned short*)(ws + o_src);
    unsigned short* dstc = (unsigned short*)(ws + o_dstc);
    float*    Tm    = ws + o_T;
    float*    Mm    = ws + o_Mm;
    unsigned short* Wb = (unsigned short*)(ws + o_Wb);

    const int NB4  = (N + 3) / 4;
    const int NB16 = (N + 15) / 16;

    // ---- dual CSR via counting sort: zero global atomics, zero memsets ----
    k_cnt    <<<EB3, 256, 0, stream>>>(ei, hist);
    k_bscan  <<<NSB, 256, 0, stream>>>(hist, pref, btot);
    k_boff   <<<1,   256, 0, stream>>>(btot, boff2, rowp);   // srcp = rowp + (N+8)
    k_scatter<<<EB3, 256, 0, stream>>>(ei, pref, boff2, sorted);
    k_csr    <<<NSB, 256, 0, stream>>>(sorted, boff2, rowp, srcc, dstc);

    // ---- W bf16 copies (one launch) ----
    k_wb3<<<192, 256, 0, stream>>>(W[0], W[1], W[2], Wb);

    // ---- 3 GAT layers (no per-layer memsets, no atomics in softmax) ----
    for (int l = 0; l < 3; l++) {
        // gemm reads previous layer's colsum/colsq (l>0); k_den zeroes them after.
        k_gemm<<<GEMM_B, 256, 0, stream>>>(x, O16, Wb + l * 16384, Hb16, att[l],
                                           ai, ajx, csum, csq, gg[l == 0 ? 0 : l - 1],
                                           be[l == 0 ? 0 : l - 1], l > 0 ? 1 : 0);
        k_den<<<NB16, 256, 0, stream>>>(srcp, dstc, ai, ajx, csum);
        k_aggregate<<<NB4, 256, 0, stream>>>(rowp, srcc, ai, ajinv, Hu2, bb[l], O16);
        k_stats<<<256, 256, 0, stream>>>(O16, csum, csq);
    }

    // ---- decoder (BN finalize for layer 3 is inlined in k_pred) ----
    k_T<<<32, 256, 0, stream>>>(P1, P2, Tm);
    k_M<<<64, 256, 0, stream>>>(Tm, P1, Mm);
    k_pred<<<1024, 128, 0, stream>>>(O16, csum, csq, gg[2], be[2], drug, Mm, (float*)d_out);
}